// Round 2
// baseline (512.177 us; speedup 1.0000x reference)
//
#include <hip/hip_runtime.h>
#include <hip/hip_bf16.h>
#include <math.h>

#define N_NODES 100000
#define N_EDGES 1600000
#define D_FEAT  64
#define BN_EPS  1e-5f

// ws layout (bytes):
//   [0, 3*N*D*2)            : k,q,v as bf16 (three N*D planes)
//   [3*N*D*2, +512)         : BN stats (64 sums + 64 sumsqs, fp32)
// h0 (skip output + edge aggregation) lives in d_out (fp32), rewritten fully
// by gemm4 every call -> deterministic under graph replay.

// ---------------------------------------------------------------------------
// Kernel 1: the four linears. blockIdx.y = which matrix (0=k,1=q,2=v,3=skip).
// Lane i caches W row i in 64 VGPRs; x[n][j] broadcast via readlane.
// ---------------------------------------------------------------------------
__global__ __launch_bounds__(256) void gemm4_kernel(
    const float* __restrict__ x,
    const float* __restrict__ Wk, const float* __restrict__ bk,
    const float* __restrict__ Wq, const float* __restrict__ bq,
    const float* __restrict__ Wv, const float* __restrict__ bv,
    const float* __restrict__ Ws, const float* __restrict__ bs,
    __hip_bfloat16* __restrict__ kqv,  // 3*N*D bf16
    float* __restrict__ h0)            // N*D fp32 (== d_out)
{
    const int m = blockIdx.y;
    const float* W; const float* b;
    if      (m == 0) { W = Wk; b = bk; }
    else if (m == 1) { W = Wq; b = bq; }
    else if (m == 2) { W = Wv; b = bv; }
    else             { W = Ws; b = bs; }

    const int lane = threadIdx.x & 63;
    const int wave = threadIdx.x >> 6;

    float w[64];
    #pragma unroll
    for (int j4 = 0; j4 < 16; ++j4) {
        const float4 t = *reinterpret_cast<const float4*>(W + lane * 64 + j4 * 4);
        w[4 * j4 + 0] = t.x; w[4 * j4 + 1] = t.y;
        w[4 * j4 + 2] = t.z; w[4 * j4 + 3] = t.w;
    }
    const float bias = b[lane];

    const int wave_id = blockIdx.x * 4 + wave;
    const int wstride = gridDim.x * 4;
    for (int n = wave_id; n < N_NODES; n += wstride) {
        const float xv = x[n * 64 + lane];
        float acc = bias;
        #pragma unroll
        for (int j = 0; j < 64; ++j) {
            const float xj = __uint_as_float(
                __builtin_amdgcn_readlane(__float_as_uint(xv), j));
            acc = fmaf(xj, w[j], acc);
        }
        if (m < 3) {
            kqv[(size_t)m * N_NODES * D_FEAT + n * 64 + lane] =
                __float2bfloat16(acc);
        } else {
            h0[n * 64 + lane] = acc;
        }
    }
}

// ---------------------------------------------------------------------------
// Kernel 2: edge aggregation. One wave per edge, lane = feature.
// h0[dst] += sigmoid(k[dst] + q[src]) * v[src]
// ---------------------------------------------------------------------------
__global__ __launch_bounds__(256) void edge_kernel(
    const int* __restrict__ ei,                 // int32! [2, E] row-major
    const __hip_bfloat16* __restrict__ kqv,
    float* __restrict__ h0)
{
    const long long tid = (long long)blockIdx.x * 256 + threadIdx.x;
    const int e = (int)(tid >> 6);
    if (e >= N_EDGES) return;
    const int i = (int)(tid & 63);
    const int s = ei[e];            // source j
    const int d = ei[N_EDGES + e];  // target i

    const __hip_bfloat16* k = kqv;
    const __hip_bfloat16* q = kqv + (size_t)1 * N_NODES * D_FEAT;
    const __hip_bfloat16* v = kqv + (size_t)2 * N_NODES * D_FEAT;

    const float kd = __bfloat162float(k[(size_t)d * D_FEAT + i]);
    const float qs = __bfloat162float(q[(size_t)s * D_FEAT + i]);
    const float vs = __bfloat162float(v[(size_t)s * D_FEAT + i]);
    const float g  = 1.0f / (1.0f + __expf(-(kd + qs)));
    atomicAdd(&h0[(size_t)d * D_FEAT + i], g * vs);
}

// ---------------------------------------------------------------------------
// Kernel 3: per-column sum / sumsq of h0 (BatchNorm stats). stats zeroed first.
// ---------------------------------------------------------------------------
__global__ __launch_bounds__(256) void stats_kernel(
    const float* __restrict__ h0, float* __restrict__ stats)
{
    __shared__ float ls[4][64];
    __shared__ float lq[4][64];
    const int col  = threadIdx.x & 63;
    const int wave = threadIdx.x >> 6;
    float s = 0.0f, q = 0.0f;
    const int stride = gridDim.x * 4;
    for (int r = blockIdx.x * 4 + wave; r < N_NODES; r += stride) {
        const float v = h0[r * D_FEAT + col];
        s += v;
        q += v * v;
    }
    ls[wave][col] = s;
    lq[wave][col] = q;
    __syncthreads();
    if (threadIdx.x < 64) {
        const float ts = ls[0][col] + ls[1][col] + ls[2][col] + ls[3][col];
        const float tq = lq[0][col] + lq[1][col] + lq[2][col] + lq[3][col];
        atomicAdd(&stats[col], ts);
        atomicAdd(&stats[64 + col], tq);
    }
}

// ---------------------------------------------------------------------------
// Kernel 4: BatchNorm (batch stats) + ReLU + residual, in-place on d_out.
// ---------------------------------------------------------------------------
__global__ __launch_bounds__(256) void final_kernel(
    float* __restrict__ h0, const float* __restrict__ x,
    const float* __restrict__ stats,
    const float* __restrict__ gamma, const float* __restrict__ beta)
{
    const float invN = 1.0f / (float)N_NODES;
    const long long total = (long long)N_NODES * D_FEAT;
    for (long long idx = (long long)blockIdx.x * 256 + threadIdx.x;
         idx < total; idx += (long long)gridDim.x * 256) {
        const int i = (int)(idx & 63);
        const float mean = stats[i] * invN;
        const float var  = stats[64 + i] * invN - mean * mean;
        const float rstd = rsqrtf(var + BN_EPS);
        float y = (h0[idx] - mean) * rstd * gamma[i] + beta[i];
        y = fmaxf(y, 0.0f) + x[idx];
        h0[idx] = y;
    }
}

// ---------------------------------------------------------------------------
extern "C" void kernel_launch(void* const* d_in, const int* in_sizes, int n_in,
                              void* d_out, int out_size, void* d_ws, size_t ws_size,
                              hipStream_t stream)
{
    const float* x     = (const float*)d_in[0];
    const int*   ei    = (const int*)d_in[1];      // int32 per harness convention
    const float* Wk    = (const float*)d_in[2];
    const float* bk    = (const float*)d_in[3];
    const float* Wq    = (const float*)d_in[4];
    const float* bq    = (const float*)d_in[5];
    const float* Wv    = (const float*)d_in[6];
    const float* bv    = (const float*)d_in[7];
    const float* Ws    = (const float*)d_in[8];
    const float* bs    = (const float*)d_in[9];
    const float* gamma = (const float*)d_in[10];
    const float* beta  = (const float*)d_in[11];

    __hip_bfloat16* kqv = (__hip_bfloat16*)d_ws;                    // 38.4 MB
    float* stats = (float*)((char*)d_ws + (size_t)3 * N_NODES * D_FEAT * 2);
    float* h0    = (float*)d_out;                                   // 25.6 MB

    // zero BN statistics accumulators (capturable async memset)
    hipMemsetAsync(stats, 0, 128 * sizeof(float), stream);

    // k, q, v (bf16 -> ws) and skip linear (fp32 -> d_out)
    gemm4_kernel<<<dim3(1024, 4), 256, 0, stream>>>(
        x, Wk, bk, Wq, bq, Wv, bv, Ws, bs, kqv, h0);

    // gated message aggregation into h0 (d_out)
    edge_kernel<<<(N_EDGES * D_FEAT) / 256, 256, 0, stream>>>(ei, kqv, h0);

    // BN column statistics
    stats_kernel<<<512, 256, 0, stream>>>(h0, stats);

    // normalize + relu + residual, in place
    final_kernel<<<2048, 256, 0, stream>>>(h0, x, stats, gamma, beta);
}

// Round 3
// 461.552 us; speedup vs baseline: 1.1097x; 1.1097x over previous
//
#include <hip/hip_runtime.h>
#include <hip/hip_bf16.h>
#include <math.h>

#define N_NODES 100000
#define N_EDGES 1600000
#define D_FEAT  64
#define BN_EPS  1e-5f
#define NCHUNK  196   // ceil(N_NODES / 512)

// ws layout (byte offsets):
//   0         : kqv bf16, 3 planes of N*D           (38,400,000 B)
//   38400000  : stats fp32[128]                     (512 B)
//   38400512  : deg int[N]                          (400,000 B)
//   38800512  : row_start int[N+1]                  (400,004 B)
//   39200516  : cursor int[N]                       (400,000 B)
//   39600516  : chunk_sums int[NCHUNK]              (784 B)
//   39601300  : chunk_off int[NCHUNK]               (784 B)
//   39602084  : sorted_src int[E]                   (6,400,000 B)
// h0 lives in d_out (fp32), fully rewritten by gemm4 every call.

// ---------------------------------------------------------------------------
// Kernel 1: four linears (0=k,1=q,2=v -> bf16 planes; 3=skip -> d_out fp32).
// ---------------------------------------------------------------------------
__global__ __launch_bounds__(256) void gemm4_kernel(
    const float* __restrict__ x,
    const float* __restrict__ Wk, const float* __restrict__ bk,
    const float* __restrict__ Wq, const float* __restrict__ bq,
    const float* __restrict__ Wv, const float* __restrict__ bv,
    const float* __restrict__ Ws, const float* __restrict__ bs,
    __hip_bfloat16* __restrict__ kqv,
    float* __restrict__ h0)
{
    const int m = blockIdx.y;
    const float* W; const float* b;
    if      (m == 0) { W = Wk; b = bk; }
    else if (m == 1) { W = Wq; b = bq; }
    else if (m == 2) { W = Wv; b = bv; }
    else             { W = Ws; b = bs; }

    const int lane = threadIdx.x & 63;
    const int wave = threadIdx.x >> 6;

    float w[64];
    #pragma unroll
    for (int j4 = 0; j4 < 16; ++j4) {
        const float4 t = *reinterpret_cast<const float4*>(W + lane * 64 + j4 * 4);
        w[4 * j4 + 0] = t.x; w[4 * j4 + 1] = t.y;
        w[4 * j4 + 2] = t.z; w[4 * j4 + 3] = t.w;
    }
    const float bias = b[lane];

    const int wave_id = blockIdx.x * 4 + wave;
    const int wstride = gridDim.x * 4;
    for (int n = wave_id; n < N_NODES; n += wstride) {
        const float xv = x[n * 64 + lane];
        float acc = bias;
        #pragma unroll
        for (int j = 0; j < 64; ++j) {
            const float xj = __uint_as_float(
                __builtin_amdgcn_readlane(__float_as_uint(xv), j));
            acc = fmaf(xj, w[j], acc);
        }
        if (m < 3) {
            kqv[(size_t)m * N_NODES * D_FEAT + n * 64 + lane] =
                __float2bfloat16(acc);
        } else {
            h0[n * 64 + lane] = acc;
        }
    }
}

// ---------------------------------------------------------------------------
// CSR build: histogram of dst degrees
// ---------------------------------------------------------------------------
__global__ __launch_bounds__(256) void hist_kernel(
    const int* __restrict__ ei, int* __restrict__ deg)
{
    const int e = blockIdx.x * 256 + threadIdx.x;
    if (e < N_EDGES) atomicAdd(&deg[ei[N_EDGES + e]], 1);
}

// Block-level exclusive scan, 512 elements per block (2 per thread).
__global__ __launch_bounds__(256) void scan1_kernel(
    const int* __restrict__ deg, int* __restrict__ row_start,
    int* __restrict__ chunk_sums)
{
    __shared__ int sh[256];
    const int t = threadIdx.x;
    const int base = blockIdx.x * 512;
    const int i0 = base + 2 * t, i1 = base + 2 * t + 1;
    const int a = (i0 < N_NODES) ? deg[i0] : 0;
    const int b = (i1 < N_NODES) ? deg[i1] : 0;
    const int s = a + b;
    sh[t] = s;
    __syncthreads();
    for (int off = 1; off < 256; off <<= 1) {
        const int val = (t >= off) ? sh[t - off] : 0;
        __syncthreads();
        sh[t] += val;
        __syncthreads();
    }
    const int excl = sh[t] - s;   // exclusive prefix of this thread's pair
    if (i0 < N_NODES) row_start[i0] = excl;
    if (i1 < N_NODES) row_start[i1] = excl + a;
    if (t == 255) chunk_sums[blockIdx.x] = sh[255];
}

// Single-block scan of the chunk totals -> exclusive chunk offsets.
__global__ __launch_bounds__(256) void scan2_kernel(
    const int* __restrict__ chunk_sums, int* __restrict__ chunk_off)
{
    __shared__ int sh[256];
    const int t = threadIdx.x;
    const int v = (t < NCHUNK) ? chunk_sums[t] : 0;
    sh[t] = v;
    __syncthreads();
    for (int off = 1; off < 256; off <<= 1) {
        const int val = (t >= off) ? sh[t - off] : 0;
        __syncthreads();
        sh[t] += val;
        __syncthreads();
    }
    if (t < NCHUNK) chunk_off[t] = sh[t] - v;
}

// Add chunk offsets; also initialize cursor = row_start and row_start[N] = E.
__global__ __launch_bounds__(256) void scan3_kernel(
    int* __restrict__ row_start, const int* __restrict__ chunk_off,
    int* __restrict__ cursor)
{
    const int off = chunk_off[blockIdx.x];
    const int base = blockIdx.x * 512;
    #pragma unroll
    for (int k = 0; k < 2; ++k) {
        const int i = base + k * 256 + threadIdx.x;
        if (i < N_NODES) {
            const int r = row_start[i] + off;
            row_start[i] = r;
            cursor[i] = r;
        }
    }
    if (blockIdx.x == 0 && threadIdx.x == 0) row_start[N_NODES] = N_EDGES;
}

// Scatter: bucket each edge's src by dst.
__global__ __launch_bounds__(256) void scatter_kernel(
    const int* __restrict__ ei, int* __restrict__ cursor,
    int* __restrict__ sorted_src)
{
    const int e = blockIdx.x * 256 + threadIdx.x;
    if (e < N_EDGES) {
        const int s = ei[e];
        const int d = ei[N_EDGES + e];
        const int pos = atomicAdd(&cursor[d], 1);
        sorted_src[pos] = s;
    }
}

// ---------------------------------------------------------------------------
// Gather: one wave per dst node; register accumulation; fused BN stats.
// ---------------------------------------------------------------------------
__global__ __launch_bounds__(256) void gather_kernel(
    const __hip_bfloat16* __restrict__ kqv,
    const int* __restrict__ row_start,
    const int* __restrict__ sorted_src,
    float* __restrict__ h0, float* __restrict__ stats)
{
    const __hip_bfloat16* kp = kqv;
    const __hip_bfloat16* qp = kqv + (size_t)1 * N_NODES * D_FEAT;
    const __hip_bfloat16* vp = kqv + (size_t)2 * N_NODES * D_FEAT;

    const int lane = threadIdx.x & 63;
    const int wave = threadIdx.x >> 6;
    float lsum = 0.0f, lsq = 0.0f;

    const int wid = blockIdx.x * 4 + wave;
    const int wstride = gridDim.x * 4;
    for (int n = wid; n < N_NODES; n += wstride) {
        const float kf = __bfloat162float(kp[(size_t)n * D_FEAT + lane]);
        float acc = h0[(size_t)n * D_FEAT + lane];   // skip-linear output
        const int base = row_start[n];
        const int end  = row_start[n + 1];
        int t = base;
        for (; t + 1 < end; t += 2) {
            const int s0 = __builtin_amdgcn_readfirstlane(sorted_src[t]);
            const int s1 = __builtin_amdgcn_readfirstlane(sorted_src[t + 1]);
            const float q0 = __bfloat162float(qp[(size_t)s0 * D_FEAT + lane]);
            const float v0 = __bfloat162float(vp[(size_t)s0 * D_FEAT + lane]);
            const float q1 = __bfloat162float(qp[(size_t)s1 * D_FEAT + lane]);
            const float v1 = __bfloat162float(vp[(size_t)s1 * D_FEAT + lane]);
            const float g0 = 1.0f / (1.0f + __expf(-(kf + q0)));
            const float g1 = 1.0f / (1.0f + __expf(-(kf + q1)));
            acc = fmaf(g0, v0, acc);
            acc = fmaf(g1, v1, acc);
        }
        if (t < end) {
            const int s0 = __builtin_amdgcn_readfirstlane(sorted_src[t]);
            const float q0 = __bfloat162float(qp[(size_t)s0 * D_FEAT + lane]);
            const float v0 = __bfloat162float(vp[(size_t)s0 * D_FEAT + lane]);
            const float g0 = 1.0f / (1.0f + __expf(-(kf + q0)));
            acc = fmaf(g0, v0, acc);
        }
        h0[(size_t)n * D_FEAT + lane] = acc;
        lsum += acc;
        lsq  += acc * acc;
    }

    __shared__ float ls[4][64];
    __shared__ float lq[4][64];
    ls[wave][lane] = lsum;
    lq[wave][lane] = lsq;
    __syncthreads();
    if (threadIdx.x < 64) {
        const float ts = ls[0][lane] + ls[1][lane] + ls[2][lane] + ls[3][lane];
        const float tq = lq[0][lane] + lq[1][lane] + lq[2][lane] + lq[3][lane];
        atomicAdd(&stats[lane], ts);
        atomicAdd(&stats[64 + lane], tq);
    }
}

// ---------------------------------------------------------------------------
// Final: BatchNorm (batch stats) + ReLU + residual, in-place on d_out.
// ---------------------------------------------------------------------------
__global__ __launch_bounds__(256) void final_kernel(
    float* __restrict__ h0, const float* __restrict__ x,
    const float* __restrict__ stats,
    const float* __restrict__ gamma, const float* __restrict__ beta)
{
    const float invN = 1.0f / (float)N_NODES;
    const long long total = (long long)N_NODES * D_FEAT;
    for (long long idx = (long long)blockIdx.x * 256 + threadIdx.x;
         idx < total; idx += (long long)gridDim.x * 256) {
        const int i = (int)(idx & 63);
        const float mean = stats[i] * invN;
        const float var  = stats[64 + i] * invN - mean * mean;
        const float rstd = rsqrtf(var + BN_EPS);
        float y = (h0[idx] - mean) * rstd * gamma[i] + beta[i];
        y = fmaxf(y, 0.0f) + x[idx];
        h0[idx] = y;
    }
}

// ---------------------------------------------------------------------------
extern "C" void kernel_launch(void* const* d_in, const int* in_sizes, int n_in,
                              void* d_out, int out_size, void* d_ws, size_t ws_size,
                              hipStream_t stream)
{
    const float* x     = (const float*)d_in[0];
    const int*   ei    = (const int*)d_in[1];
    const float* Wk    = (const float*)d_in[2];
    const float* bk    = (const float*)d_in[3];
    const float* Wq    = (const float*)d_in[4];
    const float* bq    = (const float*)d_in[5];
    const float* Wv    = (const float*)d_in[6];
    const float* bv    = (const float*)d_in[7];
    const float* Ws    = (const float*)d_in[8];
    const float* bs    = (const float*)d_in[9];
    const float* gamma = (const float*)d_in[10];
    const float* beta  = (const float*)d_in[11];

    char* w = (char*)d_ws;
    __hip_bfloat16* kqv = (__hip_bfloat16*)w;
    float* stats      = (float*)(w + 38400000);
    int*   deg        = (int*)  (w + 38400512);
    int*   row_start  = (int*)  (w + 38800512);
    int*   cursor     = (int*)  (w + 39200516);
    int*   chunk_sums = (int*)  (w + 39600516);
    int*   chunk_off  = (int*)  (w + 39601300);
    int*   sorted_src = (int*)  (w + 39602084);

    float* h0 = (float*)d_out;

    hipMemsetAsync(stats, 0, 128 * sizeof(float), stream);
    hipMemsetAsync(deg, 0, N_NODES * sizeof(int), stream);

    // k, q, v (bf16) and skip linear (fp32 -> d_out)
    gemm4_kernel<<<dim3(1024, 4), 256, 0, stream>>>(
        x, Wk, bk, Wq, bq, Wv, bv, Ws, bs, kqv, h0);

    // CSR build (overlaps gemm4 only via stream order; all on same stream)
    hist_kernel<<<6250, 256, 0, stream>>>(ei, deg);
    scan1_kernel<<<NCHUNK, 256, 0, stream>>>(deg, row_start, chunk_sums);
    scan2_kernel<<<1, 256, 0, stream>>>(chunk_sums, chunk_off);
    scan3_kernel<<<NCHUNK, 256, 0, stream>>>(row_start, chunk_off, cursor);
    scatter_kernel<<<6250, 256, 0, stream>>>(ei, cursor, sorted_src);

    // gather-side aggregation + fused BN stats
    gather_kernel<<<2048, 256, 0, stream>>>(kqv, row_start, sorted_src, h0, stats);

    // normalize + relu + residual, in place
    final_kernel<<<2048, 256, 0, stream>>>(h0, x, stats, gamma, beta);
}

// Round 4
// 360.749 us; speedup vs baseline: 1.4198x; 1.2794x over previous
//
#include <hip/hip_runtime.h>
#include <hip/hip_bf16.h>
#include <math.h>

#define N_NODES 100000
#define N_EDGES 1600000
#define D_FEAT  64
#define BN_EPS  1e-5f
#define NCHUNK  196   // ceil(N_NODES / 512)

typedef __attribute__((ext_vector_type(8))) short bf16x8;
typedef __attribute__((ext_vector_type(4))) float f32x4;

static __device__ __forceinline__ short f2bf(float f) {
    __hip_bfloat16 h = __float2bfloat16(f);
    return __builtin_bit_cast(short, h);
}

// ws layout (byte offsets):
//   0         : qv plane, [N][64] dwords (lo16=q bf16, hi16=v bf16)  (25,600,000)
//   25600000  : k plane,  [N][64] bf16                               (12,800,000)
//   38400000  : stats fp32[128]                                      (512)
//   38400512  : deg int[N]
//   38800512  : row_start int[N+1]
//   39200516  : cursor int[N]
//   39600516  : chunk_sums int[NCHUNK]
//   39601300  : chunk_off int[NCHUNK]
//   39602084  : sorted_src int[E]                                    (6,400,000)
// h0 lives in d_out (fp32), fully rewritten by the gemm every call.

// ---------------------------------------------------------------------------
// Kernel 1: four fused bf16 MFMA GEMMs. Block = 4 waves; wave w computes
// matrix w (0=k,1=q,2=v,3=skip) for a 64-row x-tile staged in LDS.
// out[n][i] = sum_j x[n][j] * W[i][j] + b[i]
// A frag: row=lane&15, k=(lane>>4)*8+e (contiguous 8).  B = W rows (B^T).
// C/D: col=lane&15, row=(lane>>4)*4+reg (m89-verified).
// LDS tile XOR-swizzled: 16B-unit' = unit ^ (row&7)  (G4).
// ---------------------------------------------------------------------------
__global__ __launch_bounds__(256) void gemm4_mfma_kernel(
    const float* __restrict__ x,
    const float* __restrict__ Wk, const float* __restrict__ bk,
    const float* __restrict__ Wq, const float* __restrict__ bq,
    const float* __restrict__ Wv, const float* __restrict__ bv,
    const float* __restrict__ Ws, const float* __restrict__ bs,
    unsigned short* __restrict__ qvp,   // [N][64] ushort pairs (q,v)
    unsigned short* __restrict__ kp,    // [N][64] bf16 bits
    float* __restrict__ h0)             // [N][64] fp32 (== d_out)
{
    __shared__ short xs[64 * 64];   // 8 KB bf16 tile, swizzled

    const int lane = threadIdx.x & 63;
    const int wave = threadIdx.x >> 6;
    const int r0 = blockIdx.x * 64;

    const float* W; const float* b;
    if      (wave == 0) { W = Wk; b = bk; }
    else if (wave == 1) { W = Wq; b = bq; }
    else if (wave == 2) { W = Wv; b = bv; }
    else                { W = Ws; b = bs; }

    // B fragments: lane holds W[col][k0..k0+7] per (nt, ks)
    const int bcol = lane & 15;
    const int bk0  = (lane >> 4) * 8;
    bf16x8 bfrag[4][2];
    #pragma unroll
    for (int nt = 0; nt < 4; ++nt) {
        #pragma unroll
        for (int ks = 0; ks < 2; ++ks) {
            const float* wp = W + (nt * 16 + bcol) * 64 + ks * 32 + bk0;
            const float4 w0 = *reinterpret_cast<const float4*>(wp);
            const float4 w1 = *reinterpret_cast<const float4*>(wp + 4);
            bf16x8 f;
            f[0] = f2bf(w0.x); f[1] = f2bf(w0.y); f[2] = f2bf(w0.z); f[3] = f2bf(w0.w);
            f[4] = f2bf(w1.x); f[5] = f2bf(w1.y); f[6] = f2bf(w1.z); f[7] = f2bf(w1.w);
            bfrag[nt][ks] = f;
        }
    }
    float biasv[4];
    #pragma unroll
    for (int nt = 0; nt < 4; ++nt) biasv[nt] = b[nt * 16 + bcol];

    // stage x-tile (fp32 -> bf16 -> LDS, swizzled); zero-pad past N
    {
        const int row = threadIdx.x >> 2;     // 0..63
        const int qd  = threadIdx.x & 3;      // column quarter
        const int grow = r0 + row;
        float4 t0, t1, t2, t3;
        if (grow < N_NODES) {
            const float* xp = x + (size_t)grow * 64 + qd * 16;
            t0 = reinterpret_cast<const float4*>(xp)[0];
            t1 = reinterpret_cast<const float4*>(xp)[1];
            t2 = reinterpret_cast<const float4*>(xp)[2];
            t3 = reinterpret_cast<const float4*>(xp)[3];
        } else {
            t0 = t1 = t2 = t3 = make_float4(0.f, 0.f, 0.f, 0.f);
        }
        bf16x8 u0, u1;
        u0[0] = f2bf(t0.x); u0[1] = f2bf(t0.y); u0[2] = f2bf(t0.z); u0[3] = f2bf(t0.w);
        u0[4] = f2bf(t1.x); u0[5] = f2bf(t1.y); u0[6] = f2bf(t1.z); u0[7] = f2bf(t1.w);
        u1[0] = f2bf(t2.x); u1[1] = f2bf(t2.y); u1[2] = f2bf(t2.z); u1[3] = f2bf(t2.w);
        u1[4] = f2bf(t3.x); u1[5] = f2bf(t3.y); u1[6] = f2bf(t3.z); u1[7] = f2bf(t3.w);
        const int sw = row & 7;
        *reinterpret_cast<bf16x8*>(xs + row * 64 + (((qd * 2)     ^ sw) * 8)) = u0;
        *reinterpret_cast<bf16x8*>(xs + row * 64 + (((qd * 2 + 1) ^ sw) * 8)) = u1;
    }
    __syncthreads();

    // MFMA: 4 M-tiles x 4 N-tiles x 2 K-steps
    f32x4 acc[4][4];
    #pragma unroll
    for (int mt = 0; mt < 4; ++mt)
        #pragma unroll
        for (int nt = 0; nt < 4; ++nt)
            acc[mt][nt] = (f32x4){biasv[nt], biasv[nt], biasv[nt], biasv[nt]};

    const int arow = lane & 15;
    const int ak   = lane >> 4;   // K-unit within K-step
    #pragma unroll
    for (int mt = 0; mt < 4; ++mt) {
        const int row = mt * 16 + arow;
        const int sw = row & 7;
        const bf16x8 a0 = *reinterpret_cast<const bf16x8*>(xs + row * 64 + ((ak       ^ sw) * 8));
        const bf16x8 a1 = *reinterpret_cast<const bf16x8*>(xs + row * 64 + (((4 + ak) ^ sw) * 8));
        #pragma unroll
        for (int nt = 0; nt < 4; ++nt) {
            acc[mt][nt] = __builtin_amdgcn_mfma_f32_16x16x32_bf16(
                a0, bfrag[nt][0], acc[mt][nt], 0, 0, 0);
            acc[mt][nt] = __builtin_amdgcn_mfma_f32_16x16x32_bf16(
                a1, bfrag[nt][1], acc[mt][nt], 0, 0, 0);
        }
    }

    // epilogue: wave 0 -> k plane (bf16), 1 -> qv.lo, 2 -> qv.hi, 3 -> h0 fp32
    const int crow0 = (lane >> 4) * 4;
    const int ccol  = lane & 15;
    #pragma unroll
    for (int mt = 0; mt < 4; ++mt) {
        #pragma unroll
        for (int nt = 0; nt < 4; ++nt) {
            #pragma unroll
            for (int r = 0; r < 4; ++r) {
                const int grow = r0 + mt * 16 + crow0 + r;
                if (grow < N_NODES) {
                    const int col = nt * 16 + ccol;
                    const float val = acc[mt][nt][r];
                    const size_t idx = (size_t)grow * 64 + col;
                    if      (wave == 0) kp[idx] = (unsigned short)f2bf(val);
                    else if (wave == 1) qvp[idx * 2]     = (unsigned short)f2bf(val);
                    else if (wave == 2) qvp[idx * 2 + 1] = (unsigned short)f2bf(val);
                    else                h0[idx] = val;
                }
            }
        }
    }
}

// ---------------------------------------------------------------------------
// CSR build
// ---------------------------------------------------------------------------
__global__ __launch_bounds__(256) void hist_kernel(
    const int* __restrict__ ei, int* __restrict__ deg)
{
    const int e = blockIdx.x * 256 + threadIdx.x;
    if (e < N_EDGES) atomicAdd(&deg[ei[N_EDGES + e]], 1);
}

__global__ __launch_bounds__(256) void scan1_kernel(
    const int* __restrict__ deg, int* __restrict__ row_start,
    int* __restrict__ chunk_sums)
{
    __shared__ int sh[256];
    const int t = threadIdx.x;
    const int base = blockIdx.x * 512;
    const int i0 = base + 2 * t, i1 = base + 2 * t + 1;
    const int a = (i0 < N_NODES) ? deg[i0] : 0;
    const int b = (i1 < N_NODES) ? deg[i1] : 0;
    const int s = a + b;
    sh[t] = s;
    __syncthreads();
    for (int off = 1; off < 256; off <<= 1) {
        const int val = (t >= off) ? sh[t - off] : 0;
        __syncthreads();
        sh[t] += val;
        __syncthreads();
    }
    const int excl = sh[t] - s;
    if (i0 < N_NODES) row_start[i0] = excl;
    if (i1 < N_NODES) row_start[i1] = excl + a;
    if (t == 255) chunk_sums[blockIdx.x] = sh[255];
}

__global__ __launch_bounds__(256) void scan2_kernel(
    const int* __restrict__ chunk_sums, int* __restrict__ chunk_off)
{
    __shared__ int sh[256];
    const int t = threadIdx.x;
    const int v = (t < NCHUNK) ? chunk_sums[t] : 0;
    sh[t] = v;
    __syncthreads();
    for (int off = 1; off < 256; off <<= 1) {
        const int val = (t >= off) ? sh[t - off] : 0;
        __syncthreads();
        sh[t] += val;
        __syncthreads();
    }
    if (t < NCHUNK) chunk_off[t] = sh[t] - v;
}

__global__ __launch_bounds__(256) void scan3_kernel(
    int* __restrict__ row_start, const int* __restrict__ chunk_off,
    int* __restrict__ cursor)
{
    const int off = chunk_off[blockIdx.x];
    const int base = blockIdx.x * 512;
    #pragma unroll
    for (int k = 0; k < 2; ++k) {
        const int i = base + k * 256 + threadIdx.x;
        if (i < N_NODES) {
            const int r = row_start[i] + off;
            row_start[i] = r;
            cursor[i] = r;
        }
    }
    if (blockIdx.x == 0 && threadIdx.x == 0) row_start[N_NODES] = N_EDGES;
}

__global__ __launch_bounds__(256) void scatter_kernel(
    const int* __restrict__ ei, int* __restrict__ cursor,
    int* __restrict__ sorted_src)
{
    const int e = blockIdx.x * 256 + threadIdx.x;
    if (e < N_EDGES) {
        const int s = ei[e];
        const int d = ei[N_EDGES + e];
        const int pos = atomicAdd(&cursor[d], 1);
        sorted_src[pos] = s;
    }
}

// ---------------------------------------------------------------------------
// Gather: one wave per dst node; src index made wave-uniform (SGPR base +
// lane*4 addressing); one dword gather per edge (packed q|v); fused BN stats.
// ---------------------------------------------------------------------------
static __device__ __forceinline__ float edge_acc(float acc, float kf, unsigned int u) {
    const float qf = __uint_as_float(u << 16);
    const float vf = __uint_as_float(u & 0xffff0000u);
    const float s  = kf + qf;
    const float e  = __expf(-s);
    const float g  = __builtin_amdgcn_rcpf(1.0f + e);
    return fmaf(g, vf, acc);
}

__global__ __launch_bounds__(256) void gather_kernel(
    const unsigned int* __restrict__ qv,     // [N][64] dwords
    const unsigned short* __restrict__ kp,   // [N][64] bf16 bits
    const int* __restrict__ row_start,
    const int* __restrict__ sorted_src,
    float* __restrict__ h0, float* __restrict__ stats)
{
    const int lane = threadIdx.x & 63;
    const int wave = threadIdx.x >> 6;
    float lsum = 0.0f, lsq = 0.0f;

    const int wid = blockIdx.x * 4 + wave;
    const int wstride = gridDim.x * 4;
    for (int n = wid; n < N_NODES; n += wstride) {
        const unsigned int kb = kp[(size_t)n * 64 + lane];
        const float kf = __uint_as_float(kb << 16);
        float acc = h0[(size_t)n * 64 + lane];
        const int base = row_start[n];
        const int end  = row_start[n + 1];
        int t = base;
        for (; t + 4 <= end; t += 4) {
            const int s0 = __builtin_amdgcn_readfirstlane(sorted_src[t + 0]);
            const int s1 = __builtin_amdgcn_readfirstlane(sorted_src[t + 1]);
            const int s2 = __builtin_amdgcn_readfirstlane(sorted_src[t + 2]);
            const int s3 = __builtin_amdgcn_readfirstlane(sorted_src[t + 3]);
            const unsigned int u0 = qv[(size_t)s0 * 64 + lane];
            const unsigned int u1 = qv[(size_t)s1 * 64 + lane];
            const unsigned int u2 = qv[(size_t)s2 * 64 + lane];
            const unsigned int u3 = qv[(size_t)s3 * 64 + lane];
            acc = edge_acc(acc, kf, u0);
            acc = edge_acc(acc, kf, u1);
            acc = edge_acc(acc, kf, u2);
            acc = edge_acc(acc, kf, u3);
        }
        for (; t < end; ++t) {
            const int s0 = __builtin_amdgcn_readfirstlane(sorted_src[t]);
            acc = edge_acc(acc, kf, qv[(size_t)s0 * 64 + lane]);
        }
        h0[(size_t)n * 64 + lane] = acc;
        lsum += acc;
        lsq  += acc * acc;
    }

    __shared__ float ls[4][64];
    __shared__ float lq[4][64];
    ls[wave][lane] = lsum;
    lq[wave][lane] = lsq;
    __syncthreads();
    if (threadIdx.x < 64) {
        const float ts = ls[0][lane] + ls[1][lane] + ls[2][lane] + ls[3][lane];
        const float tq = lq[0][lane] + lq[1][lane] + lq[2][lane] + lq[3][lane];
        atomicAdd(&stats[lane], ts);
        atomicAdd(&stats[64 + lane], tq);
    }
}

// ---------------------------------------------------------------------------
// Final: BatchNorm (batch stats) + ReLU + residual, in-place on d_out.
// ---------------------------------------------------------------------------
__global__ __launch_bounds__(256) void final_kernel(
    float* __restrict__ h0, const float* __restrict__ x,
    const float* __restrict__ stats,
    const float* __restrict__ gamma, const float* __restrict__ beta)
{
    const float invN = 1.0f / (float)N_NODES;
    const long long total = (long long)N_NODES * D_FEAT;
    for (long long idx = (long long)blockIdx.x * 256 + threadIdx.x;
         idx < total; idx += (long long)gridDim.x * 256) {
        const int i = (int)(idx & 63);
        const float mean = stats[i] * invN;
        const float var  = stats[64 + i] * invN - mean * mean;
        const float rstd = rsqrtf(var + BN_EPS);
        float y = (h0[idx] - mean) * rstd * gamma[i] + beta[i];
        y = fmaxf(y, 0.0f) + x[idx];
        h0[idx] = y;
    }
}

// ---------------------------------------------------------------------------
extern "C" void kernel_launch(void* const* d_in, const int* in_sizes, int n_in,
                              void* d_out, int out_size, void* d_ws, size_t ws_size,
                              hipStream_t stream)
{
    const float* x     = (const float*)d_in[0];
    const int*   ei    = (const int*)d_in[1];
    const float* Wk    = (const float*)d_in[2];
    const float* bk    = (const float*)d_in[3];
    const float* Wq    = (const float*)d_in[4];
    const float* bq    = (const float*)d_in[5];
    const float* Wv    = (const float*)d_in[6];
    const float* bv    = (const float*)d_in[7];
    const float* Ws    = (const float*)d_in[8];
    const float* bs    = (const float*)d_in[9];
    const float* gamma = (const float*)d_in[10];
    const float* beta  = (const float*)d_in[11];

    char* w = (char*)d_ws;
    unsigned int*   qv   = (unsigned int*)w;                 // 25.6 MB
    unsigned short* kpl  = (unsigned short*)(w + 25600000);  // 12.8 MB
    float* stats      = (float*)(w + 38400000);
    int*   deg        = (int*)  (w + 38400512);
    int*   row_start  = (int*)  (w + 38800512);
    int*   cursor     = (int*)  (w + 39200516);
    int*   chunk_sums = (int*)  (w + 39600516);
    int*   chunk_off  = (int*)  (w + 39601300);
    int*   sorted_src = (int*)  (w + 39602084);

    float* h0 = (float*)d_out;

    hipMemsetAsync(stats, 0, 128 * sizeof(float), stream);
    hipMemsetAsync(deg, 0, N_NODES * sizeof(int), stream);

    // fused MFMA linears: k,q,v (bf16 planes) + skip (fp32 -> d_out)
    gemm4_mfma_kernel<<<(N_NODES + 63) / 64, 256, 0, stream>>>(
        x, Wk, bk, Wq, bq, Wv, bv, Ws, bs, (unsigned short*)qv, kpl, h0);

    // CSR build
    hist_kernel<<<6250, 256, 0, stream>>>(ei, deg);
    scan1_kernel<<<NCHUNK, 256, 0, stream>>>(deg, row_start, chunk_sums);
    scan2_kernel<<<1, 256, 0, stream>>>(chunk_sums, chunk_off);
    scan3_kernel<<<NCHUNK, 256, 0, stream>>>(row_start, chunk_off, cursor);
    scatter_kernel<<<6250, 256, 0, stream>>>(ei, cursor, sorted_src);

    // gather-side aggregation + fused BN stats
    gather_kernel<<<2048, 256, 0, stream>>>(qv, kpl, row_start, sorted_src, h0, stats);

    // normalize + relu + residual, in place
    final_kernel<<<2048, 256, 0, stream>>>(h0, x, stats, gamma, beta);
}

// Round 5
// 219.819 us; speedup vs baseline: 2.3300x; 1.6411x over previous
//
#include <hip/hip_runtime.h>
#include <hip/hip_bf16.h>
#include <math.h>

#define N_NODES 100000
#define N_EDGES 1600000
#define D_FEAT  64
#define BN_EPS  1e-5f

#define NBUCKET_PAD 256      // padded bucket slots (196 used)
#define BUCKET_SHIFT 9       // 512 nodes per bucket
#define NBLK_E  196          // blocks in edge passes
#define EPB     8192         // edges per block (196*8192 >= E)
#define HIST_TOTAL (NBUCKET_PAD * NBLK_E)   // 50176
#define NCHUNK_H 98          // HIST_TOTAL / 512
#define DCAP    14336        // bucket staging cap (mean 8192, sd ~90)

typedef __attribute__((ext_vector_type(8))) short bf16x8;
typedef __attribute__((ext_vector_type(4))) float f32x4;

static __device__ __forceinline__ short f2bf(float f) {
    __hip_bfloat16 h = __float2bfloat16(f);
    return __builtin_bit_cast(short, h);
}

// ws layout (byte offsets):
//   0         : qv plane, [N][64] dwords (lo16=q, hi16=v)   (25,600,000)
//   25600000  : k plane,  [N][64] bf16                      (12,800,000)
//   38400000  : stats fp32[128]                             (512)
//   38400512  : blockhist int[256*196]                      (200,704)
//   38601216  : chunk_sums int[98]                          (392)
//   38601608  : chunk_off int[98]                           (392)
//   38602000  : row_start int[N+1]                          (400,004)
//   39002004  : tmp/sorted_src u32[E] (in-place reuse)      (6,400,000)
//   total 45,402,004 B

// ---------------------------------------------------------------------------
// Kernel 1: four fused bf16 MFMA GEMMs (wave w = matrix w; 64-row x-tile).
// ---------------------------------------------------------------------------
__global__ __launch_bounds__(256) void gemm4_mfma_kernel(
    const float* __restrict__ x,
    const float* __restrict__ Wk, const float* __restrict__ bk,
    const float* __restrict__ Wq, const float* __restrict__ bq,
    const float* __restrict__ Wv, const float* __restrict__ bv,
    const float* __restrict__ Ws, const float* __restrict__ bs,
    unsigned short* __restrict__ qvp,
    unsigned short* __restrict__ kp,
    float* __restrict__ h0)
{
    __shared__ short xs[64 * 64];

    const int lane = threadIdx.x & 63;
    const int wave = threadIdx.x >> 6;
    const int r0 = blockIdx.x * 64;

    const float* W; const float* b;
    if      (wave == 0) { W = Wk; b = bk; }
    else if (wave == 1) { W = Wq; b = bq; }
    else if (wave == 2) { W = Wv; b = bv; }
    else                { W = Ws; b = bs; }

    const int bcol = lane & 15;
    const int bk0  = (lane >> 4) * 8;
    bf16x8 bfrag[4][2];
    #pragma unroll
    for (int nt = 0; nt < 4; ++nt) {
        #pragma unroll
        for (int ks = 0; ks < 2; ++ks) {
            const float* wp = W + (nt * 16 + bcol) * 64 + ks * 32 + bk0;
            const float4 w0 = *reinterpret_cast<const float4*>(wp);
            const float4 w1 = *reinterpret_cast<const float4*>(wp + 4);
            bf16x8 f;
            f[0] = f2bf(w0.x); f[1] = f2bf(w0.y); f[2] = f2bf(w0.z); f[3] = f2bf(w0.w);
            f[4] = f2bf(w1.x); f[5] = f2bf(w1.y); f[6] = f2bf(w1.z); f[7] = f2bf(w1.w);
            bfrag[nt][ks] = f;
        }
    }
    float biasv[4];
    #pragma unroll
    for (int nt = 0; nt < 4; ++nt) biasv[nt] = b[nt * 16 + bcol];

    {
        const int row = threadIdx.x >> 2;
        const int qd  = threadIdx.x & 3;
        const int grow = r0 + row;
        float4 t0, t1, t2, t3;
        if (grow < N_NODES) {
            const float* xp = x + (size_t)grow * 64 + qd * 16;
            t0 = reinterpret_cast<const float4*>(xp)[0];
            t1 = reinterpret_cast<const float4*>(xp)[1];
            t2 = reinterpret_cast<const float4*>(xp)[2];
            t3 = reinterpret_cast<const float4*>(xp)[3];
        } else {
            t0 = t1 = t2 = t3 = make_float4(0.f, 0.f, 0.f, 0.f);
        }
        bf16x8 u0, u1;
        u0[0] = f2bf(t0.x); u0[1] = f2bf(t0.y); u0[2] = f2bf(t0.z); u0[3] = f2bf(t0.w);
        u0[4] = f2bf(t1.x); u0[5] = f2bf(t1.y); u0[6] = f2bf(t1.z); u0[7] = f2bf(t1.w);
        u1[0] = f2bf(t2.x); u1[1] = f2bf(t2.y); u1[2] = f2bf(t2.z); u1[3] = f2bf(t2.w);
        u1[4] = f2bf(t3.x); u1[5] = f2bf(t3.y); u1[6] = f2bf(t3.z); u1[7] = f2bf(t3.w);
        const int sw = row & 7;
        *reinterpret_cast<bf16x8*>(xs + row * 64 + (((qd * 2)     ^ sw) * 8)) = u0;
        *reinterpret_cast<bf16x8*>(xs + row * 64 + (((qd * 2 + 1) ^ sw) * 8)) = u1;
    }
    __syncthreads();

    f32x4 acc[4][4];
    #pragma unroll
    for (int mt = 0; mt < 4; ++mt)
        #pragma unroll
        for (int nt = 0; nt < 4; ++nt)
            acc[mt][nt] = (f32x4){biasv[nt], biasv[nt], biasv[nt], biasv[nt]};

    const int arow = lane & 15;
    const int ak   = lane >> 4;
    #pragma unroll
    for (int mt = 0; mt < 4; ++mt) {
        const int row = mt * 16 + arow;
        const int sw = row & 7;
        const bf16x8 a0 = *reinterpret_cast<const bf16x8*>(xs + row * 64 + ((ak       ^ sw) * 8));
        const bf16x8 a1 = *reinterpret_cast<const bf16x8*>(xs + row * 64 + (((4 + ak) ^ sw) * 8));
        #pragma unroll
        for (int nt = 0; nt < 4; ++nt) {
            acc[mt][nt] = __builtin_amdgcn_mfma_f32_16x16x32_bf16(
                a0, bfrag[nt][0], acc[mt][nt], 0, 0, 0);
            acc[mt][nt] = __builtin_amdgcn_mfma_f32_16x16x32_bf16(
                a1, bfrag[nt][1], acc[mt][nt], 0, 0, 0);
        }
    }

    const int crow0 = (lane >> 4) * 4;
    const int ccol  = lane & 15;
    #pragma unroll
    for (int mt = 0; mt < 4; ++mt) {
        #pragma unroll
        for (int nt = 0; nt < 4; ++nt) {
            #pragma unroll
            for (int r = 0; r < 4; ++r) {
                const int grow = r0 + mt * 16 + crow0 + r;
                if (grow < N_NODES) {
                    const int col = nt * 16 + ccol;
                    const float val = acc[mt][nt][r];
                    const size_t idx = (size_t)grow * 64 + col;
                    if      (wave == 0) kp[idx] = (unsigned short)f2bf(val);
                    else if (wave == 1) qvp[idx * 2]     = (unsigned short)f2bf(val);
                    else if (wave == 2) qvp[idx * 2 + 1] = (unsigned short)f2bf(val);
                    else                h0[idx] = val;
                }
            }
        }
    }
}

// ---------------------------------------------------------------------------
// CSR build, two-level radix bucketing.
// A: per-(block,bucket) histogram. Layout blockhist[bucket*NBLK_E + block].
// ---------------------------------------------------------------------------
__global__ __launch_bounds__(256) void bucket_count_kernel(
    const int* __restrict__ ei, int* __restrict__ blockhist)
{
    __shared__ int h[NBUCKET_PAD];
    h[threadIdx.x] = 0;
    __syncthreads();
    const int base = blockIdx.x * EPB;
    for (int i = threadIdx.x; i < EPB; i += 256) {
        const int e = base + i;
        if (e < N_EDGES) atomicAdd(&h[ei[N_EDGES + e] >> BUCKET_SHIFT], 1);
    }
    __syncthreads();
    blockhist[threadIdx.x * NBLK_E + blockIdx.x] = h[threadIdx.x];
}

// B: exclusive scan (in-place), 512 elements per block.
__global__ __launch_bounds__(256) void scan1_kernel(
    int* __restrict__ buf, int* __restrict__ chunk_sums, int total)
{
    __shared__ int sh[256];
    const int t = threadIdx.x;
    const int base = blockIdx.x * 512;
    const int i0 = base + 2 * t, i1 = base + 2 * t + 1;
    const int a = (i0 < total) ? buf[i0] : 0;
    const int b = (i1 < total) ? buf[i1] : 0;
    const int s = a + b;
    sh[t] = s;
    __syncthreads();
    for (int off = 1; off < 256; off <<= 1) {
        const int val = (t >= off) ? sh[t - off] : 0;
        __syncthreads();
        sh[t] += val;
        __syncthreads();
    }
    const int excl = sh[t] - s;
    if (i0 < total) buf[i0] = excl;
    if (i1 < total) buf[i1] = excl + a;
    if (t == 255) chunk_sums[blockIdx.x] = sh[255];
}

__global__ __launch_bounds__(256) void scan2_kernel(
    const int* __restrict__ chunk_sums, int* __restrict__ chunk_off, int nchunk)
{
    __shared__ int sh[256];
    const int t = threadIdx.x;
    const int v = (t < nchunk) ? chunk_sums[t] : 0;
    sh[t] = v;
    __syncthreads();
    for (int off = 1; off < 256; off <<= 1) {
        const int val = (t >= off) ? sh[t - off] : 0;
        __syncthreads();
        sh[t] += val;
        __syncthreads();
    }
    if (t < nchunk) chunk_off[t] = sh[t] - v;
}

__global__ __launch_bounds__(256) void scan3_kernel(
    int* __restrict__ buf, const int* __restrict__ chunk_off, int total)
{
    const int off = chunk_off[blockIdx.x];
    const int base = blockIdx.x * 512;
    #pragma unroll
    for (int k = 0; k < 2; ++k) {
        const int i = base + k * 256 + threadIdx.x;
        if (i < total) buf[i] += off;
    }
}

// C: scatter edges into per-(bucket,block) chunks as packed (src<<9 | dl).
__global__ __launch_bounds__(256) void bucket_scatter_kernel(
    const int* __restrict__ ei, const int* __restrict__ blockhist,
    unsigned int* __restrict__ tmp)
{
    __shared__ int cur[NBUCKET_PAD];
    cur[threadIdx.x] = blockhist[threadIdx.x * NBLK_E + blockIdx.x];
    __syncthreads();
    const int base = blockIdx.x * EPB;
    for (int i = threadIdx.x; i < EPB; i += 256) {
        const int e = base + i;
        if (e < N_EDGES) {
            const int s = ei[e];
            const int d = ei[N_EDGES + e];
            const int pos = atomicAdd(&cur[d >> BUCKET_SHIFT], 1);
            tmp[pos] = ((unsigned int)s << BUCKET_SHIFT) | (unsigned int)(d & 511);
        }
    }
}

// D: per-bucket counting sort (LDS-staged, in-place on tmp) + row_start.
__global__ __launch_bounds__(512) void bucket_sort_kernel(
    const int* __restrict__ blockhist,
    unsigned int* __restrict__ tmp,   // in: packed; out: sorted src
    int* __restrict__ row_start)
{
    __shared__ unsigned int stage[DCAP];
    __shared__ int hist[512];
    __shared__ int cursor[512];
    const int b = blockIdx.x;
    const int t = threadIdx.x;
    const int bstart = blockhist[b * NBLK_E];
    const int bend   = blockhist[(b + 1) * NBLK_E];
    int sz = bend - bstart;
    if (sz > DCAP) sz = DCAP;   // never taken statistically; avoids OOB
    for (int i = t; i < sz; i += 512) stage[i] = tmp[bstart + i];
    hist[t] = 0;
    __syncthreads();
    for (int i = t; i < sz; i += 512) atomicAdd(&hist[stage[i] & 511], 1);
    __syncthreads();
    const int myv = hist[t];
    for (int off = 1; off < 512; off <<= 1) {
        const int u = (t >= off) ? hist[t - off] : 0;
        __syncthreads();
        hist[t] += u;
        __syncthreads();
    }
    const int excl = hist[t] - myv;
    const int node = b * 512 + t;
    if (node <= N_NODES) row_start[node] = bstart + excl;
    cursor[t] = excl;
    __syncthreads();
    for (int i = t; i < sz; i += 512) {
        const unsigned int pk = stage[i];
        const int pos = atomicAdd(&cursor[(int)(pk & 511)], 1);
        tmp[bstart + pos] = pk >> BUCKET_SHIFT;
    }
}

// ---------------------------------------------------------------------------
// Gather: one wave per dst node; packed q|v dword gather; fused BN stats.
// ---------------------------------------------------------------------------
static __device__ __forceinline__ float edge_acc(float acc, float kf, unsigned int u) {
    const float qf = __uint_as_float(u << 16);
    const float vf = __uint_as_float(u & 0xffff0000u);
    const float s  = kf + qf;
    const float e  = __expf(-s);
    const float g  = __builtin_amdgcn_rcpf(1.0f + e);
    return fmaf(g, vf, acc);
}

__global__ __launch_bounds__(256) void gather_kernel(
    const unsigned int* __restrict__ qv,
    const unsigned short* __restrict__ kp,
    const int* __restrict__ row_start,
    const int* __restrict__ sorted_src,
    float* __restrict__ h0, float* __restrict__ stats)
{
    const int lane = threadIdx.x & 63;
    const int wave = threadIdx.x >> 6;
    float lsum = 0.0f, lsq = 0.0f;

    const int wid = blockIdx.x * 4 + wave;
    const int wstride = gridDim.x * 4;
    for (int n = wid; n < N_NODES; n += wstride) {
        const unsigned int kb = kp[(size_t)n * 64 + lane];
        const float kf = __uint_as_float(kb << 16);
        float acc = h0[(size_t)n * 64 + lane];
        const int base = row_start[n];
        const int end  = row_start[n + 1];
        int t = base;
        for (; t + 4 <= end; t += 4) {
            const int s0 = __builtin_amdgcn_readfirstlane(sorted_src[t + 0]);
            const int s1 = __builtin_amdgcn_readfirstlane(sorted_src[t + 1]);
            const int s2 = __builtin_amdgcn_readfirstlane(sorted_src[t + 2]);
            const int s3 = __builtin_amdgcn_readfirstlane(sorted_src[t + 3]);
            const unsigned int u0 = qv[(size_t)s0 * 64 + lane];
            const unsigned int u1 = qv[(size_t)s1 * 64 + lane];
            const unsigned int u2 = qv[(size_t)s2 * 64 + lane];
            const unsigned int u3 = qv[(size_t)s3 * 64 + lane];
            acc = edge_acc(acc, kf, u0);
            acc = edge_acc(acc, kf, u1);
            acc = edge_acc(acc, kf, u2);
            acc = edge_acc(acc, kf, u3);
        }
        for (; t < end; ++t) {
            const int s0 = __builtin_amdgcn_readfirstlane(sorted_src[t]);
            acc = edge_acc(acc, kf, qv[(size_t)s0 * 64 + lane]);
        }
        h0[(size_t)n * 64 + lane] = acc;
        lsum += acc;
        lsq  += acc * acc;
    }

    __shared__ float ls[4][64];
    __shared__ float lq[4][64];
    ls[wave][lane] = lsum;
    lq[wave][lane] = lsq;
    __syncthreads();
    if (threadIdx.x < 64) {
        const float ts = ls[0][lane] + ls[1][lane] + ls[2][lane] + ls[3][lane];
        const float tq = lq[0][lane] + lq[1][lane] + lq[2][lane] + lq[3][lane];
        atomicAdd(&stats[lane], ts);
        atomicAdd(&stats[64 + lane], tq);
    }
}

// ---------------------------------------------------------------------------
// Final: BatchNorm + ReLU + residual, in-place on d_out.
// ---------------------------------------------------------------------------
__global__ __launch_bounds__(256) void final_kernel(
    float* __restrict__ h0, const float* __restrict__ x,
    const float* __restrict__ stats,
    const float* __restrict__ gamma, const float* __restrict__ beta)
{
    const float invN = 1.0f / (float)N_NODES;
    const long long total = (long long)N_NODES * D_FEAT;
    for (long long idx = (long long)blockIdx.x * 256 + threadIdx.x;
         idx < total; idx += (long long)gridDim.x * 256) {
        const int i = (int)(idx & 63);
        const float mean = stats[i] * invN;
        const float var  = stats[64 + i] * invN - mean * mean;
        const float rstd = rsqrtf(var + BN_EPS);
        float y = (h0[idx] - mean) * rstd * gamma[i] + beta[i];
        y = fmaxf(y, 0.0f) + x[idx];
        h0[idx] = y;
    }
}

// ---------------------------------------------------------------------------
extern "C" void kernel_launch(void* const* d_in, const int* in_sizes, int n_in,
                              void* d_out, int out_size, void* d_ws, size_t ws_size,
                              hipStream_t stream)
{
    const float* x     = (const float*)d_in[0];
    const int*   ei    = (const int*)d_in[1];
    const float* Wk    = (const float*)d_in[2];
    const float* bk    = (const float*)d_in[3];
    const float* Wq    = (const float*)d_in[4];
    const float* bq    = (const float*)d_in[5];
    const float* Wv    = (const float*)d_in[6];
    const float* bv    = (const float*)d_in[7];
    const float* Ws    = (const float*)d_in[8];
    const float* bs    = (const float*)d_in[9];
    const float* gamma = (const float*)d_in[10];
    const float* beta  = (const float*)d_in[11];

    char* w = (char*)d_ws;
    unsigned int*   qv   = (unsigned int*)w;
    unsigned short* kpl  = (unsigned short*)(w + 25600000);
    float* stats      = (float*)(w + 38400000);
    int*   blockhist  = (int*)  (w + 38400512);
    int*   chunk_sums = (int*)  (w + 38601216);
    int*   chunk_off  = (int*)  (w + 38601608);
    int*   row_start  = (int*)  (w + 38602000);
    unsigned int* tmp = (unsigned int*)(w + 39002004);  // packed, then sorted src

    float* h0 = (float*)d_out;

    hipMemsetAsync(stats, 0, 128 * sizeof(float), stream);

    // fused MFMA linears: k,q,v (bf16 planes) + skip (fp32 -> d_out)
    gemm4_mfma_kernel<<<(N_NODES + 63) / 64, 256, 0, stream>>>(
        x, Wk, bk, Wq, bq, Wv, bv, Ws, bs, (unsigned short*)qv, kpl, h0);

    // CSR build, two-level bucketing
    bucket_count_kernel<<<NBLK_E, 256, 0, stream>>>(ei, blockhist);
    scan1_kernel<<<NCHUNK_H, 256, 0, stream>>>(blockhist, chunk_sums, HIST_TOTAL);
    scan2_kernel<<<1, 256, 0, stream>>>(chunk_sums, chunk_off, NCHUNK_H);
    scan3_kernel<<<NCHUNK_H, 256, 0, stream>>>(blockhist, chunk_off, HIST_TOTAL);
    bucket_scatter_kernel<<<NBLK_E, 256, 0, stream>>>(ei, blockhist, tmp);
    bucket_sort_kernel<<<196, 512, 0, stream>>>(blockhist, tmp, row_start);

    // gather-side aggregation + fused BN stats
    gather_kernel<<<2048, 256, 0, stream>>>(qv, kpl, row_start, (const int*)tmp, h0, stats);

    // normalize + relu + residual, in place
    final_kernel<<<2048, 256, 0, stream>>>(h0, x, stats, gamma, beta);
}

// Round 6
// 218.971 us; speedup vs baseline: 2.3390x; 1.0039x over previous
//
#include <hip/hip_runtime.h>
#include <hip/hip_bf16.h>
#include <math.h>

#define N_NODES 100000
#define N_EDGES 1600000
#define D_FEAT  64
#define BN_EPS  1e-5f

#define NBUCKET_PAD 256      // padded bucket slots (196 used)
#define BUCKET_SHIFT 9       // 512 nodes per bucket
#define NBLK_E  196          // blocks in edge passes
#define EPB     8192         // edges per block (196*8192 >= E)
#define HIST_TOTAL (NBUCKET_PAD * NBLK_E)   // 50176
#define NCHUNK_H 98          // HIST_TOTAL / 512
#define DCAP    14336        // bucket staging cap (mean 8192, sd ~90)

typedef __attribute__((ext_vector_type(8))) short bf16x8;
typedef __attribute__((ext_vector_type(4))) float f32x4;

static __device__ __forceinline__ short f2bf(float f) {
    __hip_bfloat16 h = __float2bfloat16(f);
    return __builtin_bit_cast(short, h);
}

// ws layout (byte offsets):
//   0         : qv plane, [N][64] dwords (lo16=q, hi16=v)   (25,600,000)
//   25600000  : k plane,  [N][64] bf16                      (12,800,000)
//   38400000  : stats fp32[128]                             (512)
//   38400512  : blockhist int[256*196]                      (200,704)
//   38601216  : chunk_sums int[98]
//   38601608  : chunk_off int[98]
//   38602000  : row_start int[N+1]                          (400,004)
//   39002004  : tmp/sorted_src u32[E] (in-place reuse)      (6,400,000)

// ---------------------------------------------------------------------------
// Kernel 1: four fused bf16 MFMA GEMMs (wave w = matrix w; 64-row x-tile).
// ---------------------------------------------------------------------------
__global__ __launch_bounds__(256) void gemm4_mfma_kernel(
    const float* __restrict__ x,
    const float* __restrict__ Wk, const float* __restrict__ bk,
    const float* __restrict__ Wq, const float* __restrict__ bq,
    const float* __restrict__ Wv, const float* __restrict__ bv,
    const float* __restrict__ Ws, const float* __restrict__ bs,
    unsigned short* __restrict__ qvp,
    unsigned short* __restrict__ kp,
    float* __restrict__ h0)
{
    __shared__ short xs[64 * 64];

    const int lane = threadIdx.x & 63;
    const int wave = threadIdx.x >> 6;
    const int r0 = blockIdx.x * 64;

    const float* W; const float* b;
    if      (wave == 0) { W = Wk; b = bk; }
    else if (wave == 1) { W = Wq; b = bq; }
    else if (wave == 2) { W = Wv; b = bv; }
    else                { W = Ws; b = bs; }

    const int bcol = lane & 15;
    const int bk0  = (lane >> 4) * 8;
    bf16x8 bfrag[4][2];
    #pragma unroll
    for (int nt = 0; nt < 4; ++nt) {
        #pragma unroll
        for (int ks = 0; ks < 2; ++ks) {
            const float* wp = W + (nt * 16 + bcol) * 64 + ks * 32 + bk0;
            const float4 w0 = *reinterpret_cast<const float4*>(wp);
            const float4 w1 = *reinterpret_cast<const float4*>(wp + 4);
            bf16x8 f;
            f[0] = f2bf(w0.x); f[1] = f2bf(w0.y); f[2] = f2bf(w0.z); f[3] = f2bf(w0.w);
            f[4] = f2bf(w1.x); f[5] = f2bf(w1.y); f[6] = f2bf(w1.z); f[7] = f2bf(w1.w);
            bfrag[nt][ks] = f;
        }
    }
    float biasv[4];
    #pragma unroll
    for (int nt = 0; nt < 4; ++nt) biasv[nt] = b[nt * 16 + bcol];

    {
        const int row = threadIdx.x >> 2;
        const int qd  = threadIdx.x & 3;
        const int grow = r0 + row;
        float4 t0, t1, t2, t3;
        if (grow < N_NODES) {
            const float* xp = x + (size_t)grow * 64 + qd * 16;
            t0 = reinterpret_cast<const float4*>(xp)[0];
            t1 = reinterpret_cast<const float4*>(xp)[1];
            t2 = reinterpret_cast<const float4*>(xp)[2];
            t3 = reinterpret_cast<const float4*>(xp)[3];
        } else {
            t0 = t1 = t2 = t3 = make_float4(0.f, 0.f, 0.f, 0.f);
        }
        bf16x8 u0, u1;
        u0[0] = f2bf(t0.x); u0[1] = f2bf(t0.y); u0[2] = f2bf(t0.z); u0[3] = f2bf(t0.w);
        u0[4] = f2bf(t1.x); u0[5] = f2bf(t1.y); u0[6] = f2bf(t1.z); u0[7] = f2bf(t1.w);
        u1[0] = f2bf(t2.x); u1[1] = f2bf(t2.y); u1[2] = f2bf(t2.z); u1[3] = f2bf(t2.w);
        u1[4] = f2bf(t3.x); u1[5] = f2bf(t3.y); u1[6] = f2bf(t3.z); u1[7] = f2bf(t3.w);
        const int sw = row & 7;
        *reinterpret_cast<bf16x8*>(xs + row * 64 + (((qd * 2)     ^ sw) * 8)) = u0;
        *reinterpret_cast<bf16x8*>(xs + row * 64 + (((qd * 2 + 1) ^ sw) * 8)) = u1;
    }
    __syncthreads();

    f32x4 acc[4][4];
    #pragma unroll
    for (int mt = 0; mt < 4; ++mt)
        #pragma unroll
        for (int nt = 0; nt < 4; ++nt)
            acc[mt][nt] = (f32x4){biasv[nt], biasv[nt], biasv[nt], biasv[nt]};

    const int arow = lane & 15;
    const int ak   = lane >> 4;
    #pragma unroll
    for (int mt = 0; mt < 4; ++mt) {
        const int row = mt * 16 + arow;
        const int sw = row & 7;
        const bf16x8 a0 = *reinterpret_cast<const bf16x8*>(xs + row * 64 + ((ak       ^ sw) * 8));
        const bf16x8 a1 = *reinterpret_cast<const bf16x8*>(xs + row * 64 + (((4 + ak) ^ sw) * 8));
        #pragma unroll
        for (int nt = 0; nt < 4; ++nt) {
            acc[mt][nt] = __builtin_amdgcn_mfma_f32_16x16x32_bf16(
                a0, bfrag[nt][0], acc[mt][nt], 0, 0, 0);
            acc[mt][nt] = __builtin_amdgcn_mfma_f32_16x16x32_bf16(
                a1, bfrag[nt][1], acc[mt][nt], 0, 0, 0);
        }
    }

    const int crow0 = (lane >> 4) * 4;
    const int ccol  = lane & 15;
    #pragma unroll
    for (int mt = 0; mt < 4; ++mt) {
        #pragma unroll
        for (int nt = 0; nt < 4; ++nt) {
            #pragma unroll
            for (int r = 0; r < 4; ++r) {
                const int grow = r0 + mt * 16 + crow0 + r;
                if (grow < N_NODES) {
                    const int col = nt * 16 + ccol;
                    const float val = acc[mt][nt][r];
                    const size_t idx = (size_t)grow * 64 + col;
                    if      (wave == 0) kp[idx] = (unsigned short)f2bf(val);
                    else if (wave == 1) qvp[idx * 2]     = (unsigned short)f2bf(val);
                    else if (wave == 2) qvp[idx * 2 + 1] = (unsigned short)f2bf(val);
                    else                h0[idx] = val;
                }
            }
        }
    }
}

// ---------------------------------------------------------------------------
// CSR build, two-level radix bucketing (unchanged from round 5).
// ---------------------------------------------------------------------------
__global__ __launch_bounds__(256) void bucket_count_kernel(
    const int* __restrict__ ei, int* __restrict__ blockhist)
{
    __shared__ int h[NBUCKET_PAD];
    h[threadIdx.x] = 0;
    __syncthreads();
    const int base = blockIdx.x * EPB;
    for (int i = threadIdx.x; i < EPB; i += 256) {
        const int e = base + i;
        if (e < N_EDGES) atomicAdd(&h[ei[N_EDGES + e] >> BUCKET_SHIFT], 1);
    }
    __syncthreads();
    blockhist[threadIdx.x * NBLK_E + blockIdx.x] = h[threadIdx.x];
}

__global__ __launch_bounds__(256) void scan1_kernel(
    int* __restrict__ buf, int* __restrict__ chunk_sums, int total)
{
    __shared__ int sh[256];
    const int t = threadIdx.x;
    const int base = blockIdx.x * 512;
    const int i0 = base + 2 * t, i1 = base + 2 * t + 1;
    const int a = (i0 < total) ? buf[i0] : 0;
    const int b = (i1 < total) ? buf[i1] : 0;
    const int s = a + b;
    sh[t] = s;
    __syncthreads();
    for (int off = 1; off < 256; off <<= 1) {
        const int val = (t >= off) ? sh[t - off] : 0;
        __syncthreads();
        sh[t] += val;
        __syncthreads();
    }
    const int excl = sh[t] - s;
    if (i0 < total) buf[i0] = excl;
    if (i1 < total) buf[i1] = excl + a;
    if (t == 255) chunk_sums[blockIdx.x] = sh[255];
}

__global__ __launch_bounds__(256) void scan2_kernel(
    const int* __restrict__ chunk_sums, int* __restrict__ chunk_off, int nchunk)
{
    __shared__ int sh[256];
    const int t = threadIdx.x;
    const int v = (t < nchunk) ? chunk_sums[t] : 0;
    sh[t] = v;
    __syncthreads();
    for (int off = 1; off < 256; off <<= 1) {
        const int val = (t >= off) ? sh[t - off] : 0;
        __syncthreads();
        sh[t] += val;
        __syncthreads();
    }
    if (t < nchunk) chunk_off[t] = sh[t] - v;
}

__global__ __launch_bounds__(256) void scan3_kernel(
    int* __restrict__ buf, const int* __restrict__ chunk_off, int total)
{
    const int off = chunk_off[blockIdx.x];
    const int base = blockIdx.x * 512;
    #pragma unroll
    for (int k = 0; k < 2; ++k) {
        const int i = base + k * 256 + threadIdx.x;
        if (i < total) buf[i] += off;
    }
}

__global__ __launch_bounds__(256) void bucket_scatter_kernel(
    const int* __restrict__ ei, const int* __restrict__ blockhist,
    unsigned int* __restrict__ tmp)
{
    __shared__ int cur[NBUCKET_PAD];
    cur[threadIdx.x] = blockhist[threadIdx.x * NBLK_E + blockIdx.x];
    __syncthreads();
    const int base = blockIdx.x * EPB;
    for (int i = threadIdx.x; i < EPB; i += 256) {
        const int e = base + i;
        if (e < N_EDGES) {
            const int s = ei[e];
            const int d = ei[N_EDGES + e];
            const int pos = atomicAdd(&cur[d >> BUCKET_SHIFT], 1);
            tmp[pos] = ((unsigned int)s << BUCKET_SHIFT) | (unsigned int)(d & 511);
        }
    }
}

__global__ __launch_bounds__(512) void bucket_sort_kernel(
    const int* __restrict__ blockhist,
    unsigned int* __restrict__ tmp,
    int* __restrict__ row_start)
{
    __shared__ unsigned int stage[DCAP];
    __shared__ int hist[512];
    __shared__ int cursor[512];
    const int b = blockIdx.x;
    const int t = threadIdx.x;
    const int bstart = blockhist[b * NBLK_E];
    const int bend   = blockhist[(b + 1) * NBLK_E];
    int sz = bend - bstart;
    if (sz > DCAP) sz = DCAP;
    for (int i = t; i < sz; i += 512) stage[i] = tmp[bstart + i];
    hist[t] = 0;
    __syncthreads();
    for (int i = t; i < sz; i += 512) atomicAdd(&hist[stage[i] & 511], 1);
    __syncthreads();
    const int myv = hist[t];
    for (int off = 1; off < 512; off <<= 1) {
        const int u = (t >= off) ? hist[t - off] : 0;
        __syncthreads();
        hist[t] += u;
        __syncthreads();
    }
    const int excl = hist[t] - myv;
    const int node = b * 512 + t;
    if (node <= N_NODES) row_start[node] = bstart + excl;
    cursor[t] = excl;
    __syncthreads();
    for (int i = t; i < sz; i += 512) {
        const unsigned int pk = stage[i];
        const int pos = atomicAdd(&cursor[(int)(pk & 511)], 1);
        tmp[bstart + pos] = pk >> BUCKET_SHIFT;
    }
}

// ---------------------------------------------------------------------------
// Gather v3: 4 nodes per wave (16 lanes/node, 4 features/lane as uint4).
// 16 row-gathers in flight per wave; same-address index loads per subgroup.
// ---------------------------------------------------------------------------
#define EDGE_F(u, kfj, accj) {                                        \
    const float qf_ = __uint_as_float((u) << 16);                     \
    const float vf_ = __uint_as_float((u) & 0xffff0000u);             \
    const float e_  = __expf(-((kfj) + qf_));                         \
    (accj) = fmaf(__builtin_amdgcn_rcpf(1.0f + e_), vf_, (accj)); }

__global__ __launch_bounds__(256, 4) void gather_kernel(
    const unsigned int* __restrict__ qv,
    const unsigned short* __restrict__ kp,
    const int* __restrict__ row_start,
    const int* __restrict__ sorted_src,
    float* __restrict__ h0, float* __restrict__ stats)
{
    const int lane = threadIdx.x & 63;
    const int sub  = lane >> 4;        // node slot within wave
    const int l    = lane & 15;        // feature quarter: features 4l..4l+3
    const int wave = threadIdx.x >> 6;

    float4 lsum = make_float4(0.f, 0.f, 0.f, 0.f);
    float4 lsq  = make_float4(0.f, 0.f, 0.f, 0.f);

    const int quad0  = blockIdx.x * 4 + wave;
    const int qstride = gridDim.x * 4;
    const int nquads = N_NODES / 4;    // 25000, exact

    for (int quad = quad0; quad < nquads; quad += qstride) {
        const int n = quad * 4 + sub;
        const int base = row_start[n];
        const int end  = row_start[n + 1];
        const int deg  = end - base;

        // wave-max degree across the 4 subgroups
        int m1 = max(deg, __shfl_xor(deg, 16));
        const int maxdeg = max(m1, __shfl_xor(m1, 32));

        // per-node row state: k (bf16x4 -> f32x4) and accumulator
        const ushort4 kr = *reinterpret_cast<const ushort4*>(kp + (size_t)n * 64 + 4 * l);
        float4 kf;
        kf.x = __uint_as_float((unsigned int)kr.x << 16);
        kf.y = __uint_as_float((unsigned int)kr.y << 16);
        kf.z = __uint_as_float((unsigned int)kr.z << 16);
        kf.w = __uint_as_float((unsigned int)kr.w << 16);
        float4 acc = *reinterpret_cast<const float4*>(h0 + (size_t)n * 64 + 4 * l);

        const int safe_last = max(min(end - 1, N_EDGES - 1), 0);

        for (int t = 0; t < maxdeg; t += 4) {
            const int i0 = min(base + t + 0, safe_last);
            const int i1 = min(base + t + 1, safe_last);
            const int i2 = min(base + t + 2, safe_last);
            const int i3 = min(base + t + 3, safe_last);
            const int s0 = sorted_src[i0];
            const int s1 = sorted_src[i1];
            const int s2 = sorted_src[i2];
            const int s3 = sorted_src[i3];
            uint4 U0 = *reinterpret_cast<const uint4*>(qv + (size_t)s0 * 64 + 4 * l);
            uint4 U1 = *reinterpret_cast<const uint4*>(qv + (size_t)s1 * 64 + 4 * l);
            uint4 U2 = *reinterpret_cast<const uint4*>(qv + (size_t)s2 * 64 + 4 * l);
            uint4 U3 = *reinterpret_cast<const uint4*>(qv + (size_t)s3 * 64 + 4 * l);
            // mask invalid edge slots: u=0 -> v=0 -> zero contribution
            const bool v0 = (t + 0) < deg, v1 = (t + 1) < deg,
                       v2 = (t + 2) < deg, v3 = (t + 3) < deg;
            U0.x = v0 ? U0.x : 0u; U0.y = v0 ? U0.y : 0u; U0.z = v0 ? U0.z : 0u; U0.w = v0 ? U0.w : 0u;
            U1.x = v1 ? U1.x : 0u; U1.y = v1 ? U1.y : 0u; U1.z = v1 ? U1.z : 0u; U1.w = v1 ? U1.w : 0u;
            U2.x = v2 ? U2.x : 0u; U2.y = v2 ? U2.y : 0u; U2.z = v2 ? U2.z : 0u; U2.w = v2 ? U2.w : 0u;
            U3.x = v3 ? U3.x : 0u; U3.y = v3 ? U3.y : 0u; U3.z = v3 ? U3.z : 0u; U3.w = v3 ? U3.w : 0u;

            EDGE_F(U0.x, kf.x, acc.x) EDGE_F(U0.y, kf.y, acc.y)
            EDGE_F(U0.z, kf.z, acc.z) EDGE_F(U0.w, kf.w, acc.w)
            EDGE_F(U1.x, kf.x, acc.x) EDGE_F(U1.y, kf.y, acc.y)
            EDGE_F(U1.z, kf.z, acc.z) EDGE_F(U1.w, kf.w, acc.w)
            EDGE_F(U2.x, kf.x, acc.x) EDGE_F(U2.y, kf.y, acc.y)
            EDGE_F(U2.z, kf.z, acc.z) EDGE_F(U2.w, kf.w, acc.w)
            EDGE_F(U3.x, kf.x, acc.x) EDGE_F(U3.y, kf.y, acc.y)
            EDGE_F(U3.z, kf.z, acc.z) EDGE_F(U3.w, kf.w, acc.w)
        }

        *reinterpret_cast<float4*>(h0 + (size_t)n * 64 + 4 * l) = acc;
        lsum.x += acc.x; lsum.y += acc.y; lsum.z += acc.z; lsum.w += acc.w;
        lsq.x += acc.x * acc.x; lsq.y += acc.y * acc.y;
        lsq.z += acc.z * acc.z; lsq.w += acc.w * acc.w;
    }

    // block-level BN stats reduce (feature f = 4l+j gets 16 contributors)
    __shared__ float bsum[64];
    __shared__ float bsq[64];
    if (threadIdx.x < 64) { bsum[threadIdx.x] = 0.f; bsq[threadIdx.x] = 0.f; }
    __syncthreads();
    atomicAdd(&bsum[4 * l + 0], lsum.x); atomicAdd(&bsq[4 * l + 0], lsq.x);
    atomicAdd(&bsum[4 * l + 1], lsum.y); atomicAdd(&bsq[4 * l + 1], lsq.y);
    atomicAdd(&bsum[4 * l + 2], lsum.z); atomicAdd(&bsq[4 * l + 2], lsq.z);
    atomicAdd(&bsum[4 * l + 3], lsum.w); atomicAdd(&bsq[4 * l + 3], lsq.w);
    __syncthreads();
    if (threadIdx.x < 64) {
        atomicAdd(&stats[threadIdx.x], bsum[threadIdx.x]);
        atomicAdd(&stats[64 + threadIdx.x], bsq[threadIdx.x]);
    }
}

// ---------------------------------------------------------------------------
// Final: BatchNorm + ReLU + residual, in-place on d_out.
// ---------------------------------------------------------------------------
__global__ __launch_bounds__(256) void final_kernel(
    float* __restrict__ h0, const float* __restrict__ x,
    const float* __restrict__ stats,
    const float* __restrict__ gamma, const float* __restrict__ beta)
{
    const float invN = 1.0f / (float)N_NODES;
    const long long total = (long long)N_NODES * D_FEAT;
    for (long long idx = (long long)blockIdx.x * 256 + threadIdx.x;
         idx < total; idx += (long long)gridDim.x * 256) {
        const int i = (int)(idx & 63);
        const float mean = stats[i] * invN;
        const float var  = stats[64 + i] * invN - mean * mean;
        const float rstd = rsqrtf(var + BN_EPS);
        float y = (h0[idx] - mean) * rstd * gamma[i] + beta[i];
        y = fmaxf(y, 0.0f) + x[idx];
        h0[idx] = y;
    }
}

// ---------------------------------------------------------------------------
extern "C" void kernel_launch(void* const* d_in, const int* in_sizes, int n_in,
                              void* d_out, int out_size, void* d_ws, size_t ws_size,
                              hipStream_t stream)
{
    const float* x     = (const float*)d_in[0];
    const int*   ei    = (const int*)d_in[1];
    const float* Wk    = (const float*)d_in[2];
    const float* bk    = (const float*)d_in[3];
    const float* Wq    = (const float*)d_in[4];
    const float* bq    = (const float*)d_in[5];
    const float* Wv    = (const float*)d_in[6];
    const float* bv    = (const float*)d_in[7];
    const float* Ws    = (const float*)d_in[8];
    const float* bs    = (const float*)d_in[9];
    const float* gamma = (const float*)d_in[10];
    const float* beta  = (const float*)d_in[11];

    char* w = (char*)d_ws;
    unsigned int*   qv   = (unsigned int*)w;
    unsigned short* kpl  = (unsigned short*)(w + 25600000);
    float* stats      = (float*)(w + 38400000);
    int*   blockhist  = (int*)  (w + 38400512);
    int*   chunk_sums = (int*)  (w + 38601216);
    int*   chunk_off  = (int*)  (w + 38601608);
    int*   row_start  = (int*)  (w + 38602000);
    unsigned int* tmp = (unsigned int*)(w + 39002004);

    float* h0 = (float*)d_out;

    hipMemsetAsync(stats, 0, 128 * sizeof(float), stream);

    gemm4_mfma_kernel<<<(N_NODES + 63) / 64, 256, 0, stream>>>(
        x, Wk, bk, Wq, bq, Wv, bv, Ws, bs, (unsigned short*)qv, kpl, h0);

    bucket_count_kernel<<<NBLK_E, 256, 0, stream>>>(ei, blockhist);
    scan1_kernel<<<NCHUNK_H, 256, 0, stream>>>(blockhist, chunk_sums, HIST_TOTAL);
    scan2_kernel<<<1, 256, 0, stream>>>(chunk_sums, chunk_off, NCHUNK_H);
    scan3_kernel<<<NCHUNK_H, 256, 0, stream>>>(blockhist, chunk_off, HIST_TOTAL);
    bucket_scatter_kernel<<<NBLK_E, 256, 0, stream>>>(ei, blockhist, tmp);
    bucket_sort_kernel<<<196, 512, 0, stream>>>(blockhist, tmp, row_start);

    gather_kernel<<<2084, 256, 0, stream>>>(qv, kpl, row_start, (const int*)tmp, h0, stats);

    final_kernel<<<2048, 256, 0, stream>>>(h0, x, stats, gamma, beta);
}

// Round 7
// 200.410 us; speedup vs baseline: 2.5556x; 1.0926x over previous
//
#include <hip/hip_runtime.h>
#include <hip/hip_bf16.h>
#include <math.h>

#define N_NODES 100000
#define N_EDGES 1600000
#define D_FEAT  64
#define BN_EPS  1e-5f

#define NBUCKET_PAD 256      // padded bucket slots (196 used)
#define BUCKET_SHIFT 9       // 512 nodes per bucket
#define NBLK_E  196          // blocks in edge passes
#define EPB     8192         // edges per block (196*8192 >= E)
#define HIST_TOTAL (NBUCKET_PAD * NBLK_E)   // 50176
#define NCHUNK_H 98          // HIST_TOTAL / 512
#define DCAP    14336        // bucket staging cap (mean 8192, sd ~90)
#define GEMM_BLOCKS 1563     // ceil(N_NODES / 64)

typedef __attribute__((ext_vector_type(8))) short bf16x8;
typedef __attribute__((ext_vector_type(4))) float f32x4;

static __device__ __forceinline__ short f2bf(float f) {
    __hip_bfloat16 h = __float2bfloat16(f);
    return __builtin_bit_cast(short, h);
}

// ws layout (byte offsets):
//   0         : qv plane, [N][64] dwords (lo16=q, hi16=v)   (25,600,000)
//   25600000  : k plane,  [N][64] bf16                      (12,800,000)
//   38400000  : stats fp32[128]                             (512)
//   38400512  : blockhist int[256*196]                      (200,704)
//   38601216  : chunk_sums int[98]
//   38601608  : chunk_off int[98]
//   38602000  : row_start int[N+1]                          (400,004)
//   39002004  : tmp/sorted_src u32[E] (in-place reuse)      (6,400,000)

// ---------------------------------------------------------------------------
// Kernel 1 (fused): blocks [0,GEMM_BLOCKS) = four bf16 MFMA linears with
// LDS-repacked coalesced epilogue; blocks [GEMM_BLOCKS, +NBLK_E) = edge
// bucket histogram (independent work, hidden under the GEMM).
// ---------------------------------------------------------------------------
__global__ __launch_bounds__(256) void gemm4_count_kernel(
    const float* __restrict__ x,
    const float* __restrict__ Wk, const float* __restrict__ bk,
    const float* __restrict__ Wq, const float* __restrict__ bq,
    const float* __restrict__ Wv, const float* __restrict__ bv,
    const float* __restrict__ Ws, const float* __restrict__ bs,
    unsigned int* __restrict__ qv,      // [N][64] packed q|v dwords
    unsigned short* __restrict__ kp,    // [N][64] bf16 bits
    float* __restrict__ h0,             // [N][64] fp32 (== d_out)
    const int* __restrict__ ei, int* __restrict__ blockhist)
{
    __shared__ short xs[64 * 64];            // 8 KB staging tile
    __shared__ unsigned short kt[64][68];    // padded repack tiles (8.5 KB each)
    __shared__ unsigned short qt[64][68];
    __shared__ unsigned short vt[64][68];
    __shared__ int hcnt[NBUCKET_PAD];

    // ---------------- bucket-count path ----------------
    if (blockIdx.x >= GEMM_BLOCKS) {
        const int cb = blockIdx.x - GEMM_BLOCKS;
        hcnt[threadIdx.x] = 0;
        __syncthreads();
        const int base = cb * EPB;
        for (int i = threadIdx.x; i < EPB; i += 256) {
            const int e = base + i;
            if (e < N_EDGES) atomicAdd(&hcnt[ei[N_EDGES + e] >> BUCKET_SHIFT], 1);
        }
        __syncthreads();
        blockhist[threadIdx.x * NBLK_E + cb] = hcnt[threadIdx.x];
        return;
    }

    // ---------------- GEMM path ----------------
    const int lane = threadIdx.x & 63;
    const int wave = threadIdx.x >> 6;
    const int r0 = blockIdx.x * 64;

    const float* W; const float* b;
    if      (wave == 0) { W = Wk; b = bk; }
    else if (wave == 1) { W = Wq; b = bq; }
    else if (wave == 2) { W = Wv; b = bv; }
    else                { W = Ws; b = bs; }

    const int bcol = lane & 15;
    const int bk0  = (lane >> 4) * 8;
    bf16x8 bfrag[4][2];
    #pragma unroll
    for (int nt = 0; nt < 4; ++nt) {
        #pragma unroll
        for (int ks = 0; ks < 2; ++ks) {
            const float* wp = W + (nt * 16 + bcol) * 64 + ks * 32 + bk0;
            const float4 w0 = *reinterpret_cast<const float4*>(wp);
            const float4 w1 = *reinterpret_cast<const float4*>(wp + 4);
            bf16x8 f;
            f[0] = f2bf(w0.x); f[1] = f2bf(w0.y); f[2] = f2bf(w0.z); f[3] = f2bf(w0.w);
            f[4] = f2bf(w1.x); f[5] = f2bf(w1.y); f[6] = f2bf(w1.z); f[7] = f2bf(w1.w);
            bfrag[nt][ks] = f;
        }
    }
    float biasv[4];
    #pragma unroll
    for (int nt = 0; nt < 4; ++nt) biasv[nt] = b[nt * 16 + bcol];

    {
        const int row = threadIdx.x >> 2;
        const int qd  = threadIdx.x & 3;
        const int grow = r0 + row;
        float4 t0, t1, t2, t3;
        if (grow < N_NODES) {
            const float* xp = x + (size_t)grow * 64 + qd * 16;
            t0 = reinterpret_cast<const float4*>(xp)[0];
            t1 = reinterpret_cast<const float4*>(xp)[1];
            t2 = reinterpret_cast<const float4*>(xp)[2];
            t3 = reinterpret_cast<const float4*>(xp)[3];
        } else {
            t0 = t1 = t2 = t3 = make_float4(0.f, 0.f, 0.f, 0.f);
        }
        bf16x8 u0, u1;
        u0[0] = f2bf(t0.x); u0[1] = f2bf(t0.y); u0[2] = f2bf(t0.z); u0[3] = f2bf(t0.w);
        u0[4] = f2bf(t1.x); u0[5] = f2bf(t1.y); u0[6] = f2bf(t1.z); u0[7] = f2bf(t1.w);
        u1[0] = f2bf(t2.x); u1[1] = f2bf(t2.y); u1[2] = f2bf(t2.z); u1[3] = f2bf(t2.w);
        u1[4] = f2bf(t3.x); u1[5] = f2bf(t3.y); u1[6] = f2bf(t3.z); u1[7] = f2bf(t3.w);
        const int sw = row & 7;
        *reinterpret_cast<bf16x8*>(xs + row * 64 + (((qd * 2)     ^ sw) * 8)) = u0;
        *reinterpret_cast<bf16x8*>(xs + row * 64 + (((qd * 2 + 1) ^ sw) * 8)) = u1;
    }
    __syncthreads();

    f32x4 acc[4][4];
    #pragma unroll
    for (int mt = 0; mt < 4; ++mt)
        #pragma unroll
        for (int nt = 0; nt < 4; ++nt)
            acc[mt][nt] = (f32x4){biasv[nt], biasv[nt], biasv[nt], biasv[nt]};

    const int arow = lane & 15;
    const int ak   = lane >> 4;
    #pragma unroll
    for (int mt = 0; mt < 4; ++mt) {
        const int row = mt * 16 + arow;
        const int sw = row & 7;
        const bf16x8 a0 = *reinterpret_cast<const bf16x8*>(xs + row * 64 + ((ak       ^ sw) * 8));
        const bf16x8 a1 = *reinterpret_cast<const bf16x8*>(xs + row * 64 + (((4 + ak) ^ sw) * 8));
        #pragma unroll
        for (int nt = 0; nt < 4; ++nt) {
            acc[mt][nt] = __builtin_amdgcn_mfma_f32_16x16x32_bf16(
                a0, bfrag[nt][0], acc[mt][nt], 0, 0, 0);
            acc[mt][nt] = __builtin_amdgcn_mfma_f32_16x16x32_bf16(
                a1, bfrag[nt][1], acc[mt][nt], 0, 0, 0);
        }
    }

    // epilogue: waves 0/1/2 stash bf16 results in LDS; wave 3 stores h0 fp32.
    const int crow0 = (lane >> 4) * 4;
    const int ccol  = lane & 15;
    if (wave < 3) {
        unsigned short (*tile)[68] = (wave == 0) ? kt : (wave == 1) ? qt : vt;
        #pragma unroll
        for (int mt = 0; mt < 4; ++mt)
            #pragma unroll
            for (int nt = 0; nt < 4; ++nt)
                #pragma unroll
                for (int r = 0; r < 4; ++r)
                    tile[mt * 16 + crow0 + r][nt * 16 + ccol] =
                        (unsigned short)f2bf(acc[mt][nt][r]);
    } else {
        #pragma unroll
        for (int mt = 0; mt < 4; ++mt)
            #pragma unroll
            for (int nt = 0; nt < 4; ++nt)
                #pragma unroll
                for (int r = 0; r < 4; ++r) {
                    const int grow = r0 + mt * 16 + crow0 + r;
                    if (grow < N_NODES)
                        h0[(size_t)grow * 64 + nt * 16 + ccol] = acc[mt][nt][r];
                }
    }
    __syncthreads();

    // cooperative coalesced flush: thread -> (row, 16-col segment)
    {
        const int row = threadIdx.x >> 2;
        const int seg = threadIdx.x & 3;
        const int grow = r0 + row;
        if (grow < N_NODES) {
            const int c0 = seg * 16;
            unsigned int qd[16];
            #pragma unroll
            for (int i = 0; i < 16; ++i)
                qd[i] = (unsigned int)qt[row][c0 + i] |
                        ((unsigned int)vt[row][c0 + i] << 16);
            uint4* qdst = reinterpret_cast<uint4*>(qv + (size_t)grow * 64 + c0);
            qdst[0] = make_uint4(qd[0],  qd[1],  qd[2],  qd[3]);
            qdst[1] = make_uint4(qd[4],  qd[5],  qd[6],  qd[7]);
            qdst[2] = make_uint4(qd[8],  qd[9],  qd[10], qd[11]);
            qdst[3] = make_uint4(qd[12], qd[13], qd[14], qd[15]);

            unsigned int kd[8];
            #pragma unroll
            for (int i = 0; i < 8; ++i)
                kd[i] = (unsigned int)kt[row][c0 + 2 * i] |
                        ((unsigned int)kt[row][c0 + 2 * i + 1] << 16);
            uint4* kdst = reinterpret_cast<uint4*>(kp + (size_t)grow * 64 + c0);
            kdst[0] = make_uint4(kd[0], kd[1], kd[2], kd[3]);
            kdst[1] = make_uint4(kd[4], kd[5], kd[6], kd[7]);
        }
    }
}

// ---------------------------------------------------------------------------
// CSR build: scans + scatter + per-bucket counting sort (unchanged).
// ---------------------------------------------------------------------------
__global__ __launch_bounds__(256) void scan1_kernel(
    int* __restrict__ buf, int* __restrict__ chunk_sums, int total)
{
    __shared__ int sh[256];
    const int t = threadIdx.x;
    const int base = blockIdx.x * 512;
    const int i0 = base + 2 * t, i1 = base + 2 * t + 1;
    const int a = (i0 < total) ? buf[i0] : 0;
    const int b = (i1 < total) ? buf[i1] : 0;
    const int s = a + b;
    sh[t] = s;
    __syncthreads();
    for (int off = 1; off < 256; off <<= 1) {
        const int val = (t >= off) ? sh[t - off] : 0;
        __syncthreads();
        sh[t] += val;
        __syncthreads();
    }
    const int excl = sh[t] - s;
    if (i0 < total) buf[i0] = excl;
    if (i1 < total) buf[i1] = excl + a;
    if (t == 255) chunk_sums[blockIdx.x] = sh[255];
}

__global__ __launch_bounds__(256) void scan2_kernel(
    const int* __restrict__ chunk_sums, int* __restrict__ chunk_off, int nchunk)
{
    __shared__ int sh[256];
    const int t = threadIdx.x;
    const int v = (t < nchunk) ? chunk_sums[t] : 0;
    sh[t] = v;
    __syncthreads();
    for (int off = 1; off < 256; off <<= 1) {
        const int val = (t >= off) ? sh[t - off] : 0;
        __syncthreads();
        sh[t] += val;
        __syncthreads();
    }
    if (t < nchunk) chunk_off[t] = sh[t] - v;
}

__global__ __launch_bounds__(256) void scan3_kernel(
    int* __restrict__ buf, const int* __restrict__ chunk_off, int total)
{
    const int off = chunk_off[blockIdx.x];
    const int base = blockIdx.x * 512;
    #pragma unroll
    for (int k = 0; k < 2; ++k) {
        const int i = base + k * 256 + threadIdx.x;
        if (i < total) buf[i] += off;
    }
}

__global__ __launch_bounds__(256) void bucket_scatter_kernel(
    const int* __restrict__ ei, const int* __restrict__ blockhist,
    unsigned int* __restrict__ tmp)
{
    __shared__ int cur[NBUCKET_PAD];
    cur[threadIdx.x] = blockhist[threadIdx.x * NBLK_E + blockIdx.x];
    __syncthreads();
    const int base = blockIdx.x * EPB;
    for (int i = threadIdx.x; i < EPB; i += 256) {
        const int e = base + i;
        if (e < N_EDGES) {
            const int s = ei[e];
            const int d = ei[N_EDGES + e];
            const int pos = atomicAdd(&cur[d >> BUCKET_SHIFT], 1);
            tmp[pos] = ((unsigned int)s << BUCKET_SHIFT) | (unsigned int)(d & 511);
        }
    }
}

__global__ __launch_bounds__(512) void bucket_sort_kernel(
    const int* __restrict__ blockhist,
    unsigned int* __restrict__ tmp,
    int* __restrict__ row_start)
{
    __shared__ unsigned int stage[DCAP];
    __shared__ int hist[512];
    __shared__ int cursor[512];
    const int b = blockIdx.x;
    const int t = threadIdx.x;
    const int bstart = blockhist[b * NBLK_E];
    const int bend   = blockhist[(b + 1) * NBLK_E];
    int sz = bend - bstart;
    if (sz > DCAP) sz = DCAP;
    for (int i = t; i < sz; i += 512) stage[i] = tmp[bstart + i];
    hist[t] = 0;
    __syncthreads();
    for (int i = t; i < sz; i += 512) atomicAdd(&hist[stage[i] & 511], 1);
    __syncthreads();
    const int myv = hist[t];
    for (int off = 1; off < 512; off <<= 1) {
        const int u = (t >= off) ? hist[t - off] : 0;
        __syncthreads();
        hist[t] += u;
        __syncthreads();
    }
    const int excl = hist[t] - myv;
    const int node = b * 512 + t;
    if (node <= N_NODES) row_start[node] = bstart + excl;
    cursor[t] = excl;
    __syncthreads();
    for (int i = t; i < sz; i += 512) {
        const unsigned int pk = stage[i];
        const int pos = atomicAdd(&cursor[(int)(pk & 511)], 1);
        tmp[bstart + pos] = pk >> BUCKET_SHIFT;
    }
}

// ---------------------------------------------------------------------------
// Gather: 4 nodes per wave (16 lanes/node, uint4/lane); fused BN stats.
// Throughput-limited on the L2-miss path (~2.1 TB/s) — near structural floor.
// ---------------------------------------------------------------------------
#define EDGE_F(u, kfj, accj) {                                        \
    const float qf_ = __uint_as_float((u) << 16);                     \
    const float vf_ = __uint_as_float((u) & 0xffff0000u);             \
    const float e_  = __expf(-((kfj) + qf_));                         \
    (accj) = fmaf(__builtin_amdgcn_rcpf(1.0f + e_), vf_, (accj)); }

__global__ __launch_bounds__(256, 4) void gather_kernel(
    const unsigned int* __restrict__ qv,
    const unsigned short* __restrict__ kp,
    const int* __restrict__ row_start,
    const int* __restrict__ sorted_src,
    float* __restrict__ h0, float* __restrict__ stats)
{
    const int lane = threadIdx.x & 63;
    const int sub  = lane >> 4;
    const int l    = lane & 15;
    const int wave = threadIdx.x >> 6;

    float4 lsum = make_float4(0.f, 0.f, 0.f, 0.f);
    float4 lsq  = make_float4(0.f, 0.f, 0.f, 0.f);

    const int quad0  = blockIdx.x * 4 + wave;
    const int qstride = gridDim.x * 4;
    const int nquads = N_NODES / 4;

    for (int quad = quad0; quad < nquads; quad += qstride) {
        const int n = quad * 4 + sub;
        const int base = row_start[n];
        const int end  = row_start[n + 1];
        const int deg  = end - base;

        int m1 = max(deg, __shfl_xor(deg, 16));
        const int maxdeg = max(m1, __shfl_xor(m1, 32));

        const ushort4 kr = *reinterpret_cast<const ushort4*>(kp + (size_t)n * 64 + 4 * l);
        float4 kf;
        kf.x = __uint_as_float((unsigned int)kr.x << 16);
        kf.y = __uint_as_float((unsigned int)kr.y << 16);
        kf.z = __uint_as_float((unsigned int)kr.z << 16);
        kf.w = __uint_as_float((unsigned int)kr.w << 16);
        float4 acc = *reinterpret_cast<const float4*>(h0 + (size_t)n * 64 + 4 * l);

        const int safe_last = max(min(end - 1, N_EDGES - 1), 0);

        for (int t = 0; t < maxdeg; t += 4) {
            const int i0 = min(base + t + 0, safe_last);
            const int i1 = min(base + t + 1, safe_last);
            const int i2 = min(base + t + 2, safe_last);
            const int i3 = min(base + t + 3, safe_last);
            const int s0 = sorted_src[i0];
            const int s1 = sorted_src[i1];
            const int s2 = sorted_src[i2];
            const int s3 = sorted_src[i3];
            uint4 U0 = *reinterpret_cast<const uint4*>(qv + (size_t)s0 * 64 + 4 * l);
            uint4 U1 = *reinterpret_cast<const uint4*>(qv + (size_t)s1 * 64 + 4 * l);
            uint4 U2 = *reinterpret_cast<const uint4*>(qv + (size_t)s2 * 64 + 4 * l);
            uint4 U3 = *reinterpret_cast<const uint4*>(qv + (size_t)s3 * 64 + 4 * l);
            const bool v0 = (t + 0) < deg, v1 = (t + 1) < deg,
                       v2 = (t + 2) < deg, v3 = (t + 3) < deg;
            U0.x = v0 ? U0.x : 0u; U0.y = v0 ? U0.y : 0u; U0.z = v0 ? U0.z : 0u; U0.w = v0 ? U0.w : 0u;
            U1.x = v1 ? U1.x : 0u; U1.y = v1 ? U1.y : 0u; U1.z = v1 ? U1.z : 0u; U1.w = v1 ? U1.w : 0u;
            U2.x = v2 ? U2.x : 0u; U2.y = v2 ? U2.y : 0u; U2.z = v2 ? U2.z : 0u; U2.w = v2 ? U2.w : 0u;
            U3.x = v3 ? U3.x : 0u; U3.y = v3 ? U3.y : 0u; U3.z = v3 ? U3.z : 0u; U3.w = v3 ? U3.w : 0u;

            EDGE_F(U0.x, kf.x, acc.x) EDGE_F(U0.y, kf.y, acc.y)
            EDGE_F(U0.z, kf.z, acc.z) EDGE_F(U0.w, kf.w, acc.w)
            EDGE_F(U1.x, kf.x, acc.x) EDGE_F(U1.y, kf.y, acc.y)
            EDGE_F(U1.z, kf.z, acc.z) EDGE_F(U1.w, kf.w, acc.w)
            EDGE_F(U2.x, kf.x, acc.x) EDGE_F(U2.y, kf.y, acc.y)
            EDGE_F(U2.z, kf.z, acc.z) EDGE_F(U2.w, kf.w, acc.w)
            EDGE_F(U3.x, kf.x, acc.x) EDGE_F(U3.y, kf.y, acc.y)
            EDGE_F(U3.z, kf.z, acc.z) EDGE_F(U3.w, kf.w, acc.w)
        }

        *reinterpret_cast<float4*>(h0 + (size_t)n * 64 + 4 * l) = acc;
        lsum.x += acc.x; lsum.y += acc.y; lsum.z += acc.z; lsum.w += acc.w;
        lsq.x += acc.x * acc.x; lsq.y += acc.y * acc.y;
        lsq.z += acc.z * acc.z; lsq.w += acc.w * acc.w;
    }

    __shared__ float bsum[64];
    __shared__ float bsq[64];
    if (threadIdx.x < 64) { bsum[threadIdx.x] = 0.f; bsq[threadIdx.x] = 0.f; }
    __syncthreads();
    atomicAdd(&bsum[4 * l + 0], lsum.x); atomicAdd(&bsq[4 * l + 0], lsq.x);
    atomicAdd(&bsum[4 * l + 1], lsum.y); atomicAdd(&bsq[4 * l + 1], lsq.y);
    atomicAdd(&bsum[4 * l + 2], lsum.z); atomicAdd(&bsq[4 * l + 2], lsq.z);
    atomicAdd(&bsum[4 * l + 3], lsum.w); atomicAdd(&bsq[4 * l + 3], lsq.w);
    __syncthreads();
    if (threadIdx.x < 64) {
        atomicAdd(&stats[threadIdx.x], bsum[threadIdx.x]);
        atomicAdd(&stats[64 + threadIdx.x], bsq[threadIdx.x]);
    }
}

// ---------------------------------------------------------------------------
// Final v2: BN + ReLU + residual; quad mapping mirrors gather (same grid)
// so h0 reads hit the same XCD's L2; stats hoisted; float4 everywhere.
// ---------------------------------------------------------------------------
__global__ __launch_bounds__(256) void final_kernel(
    float* __restrict__ h0, const float* __restrict__ x,
    const float* __restrict__ stats,
    const float* __restrict__ gamma, const float* __restrict__ beta)
{
    const int lane = threadIdx.x & 63;
    const int sub  = lane >> 4;
    const int l    = lane & 15;
    const int wave = threadIdx.x >> 6;

    const float invN = 1.0f / (float)N_NODES;
    const float4 s1 = *reinterpret_cast<const float4*>(stats + 4 * l);
    const float4 s2 = *reinterpret_cast<const float4*>(stats + 64 + 4 * l);
    const float4 g  = *reinterpret_cast<const float4*>(gamma + 4 * l);
    const float4 bt = *reinterpret_cast<const float4*>(beta + 4 * l);
    float4 mean, a;
    mean.x = s1.x * invN; mean.y = s1.y * invN;
    mean.z = s1.z * invN; mean.w = s1.w * invN;
    a.x = rsqrtf(s2.x * invN - mean.x * mean.x + BN_EPS) * g.x;
    a.y = rsqrtf(s2.y * invN - mean.y * mean.y + BN_EPS) * g.y;
    a.z = rsqrtf(s2.z * invN - mean.z * mean.z + BN_EPS) * g.z;
    a.w = rsqrtf(s2.w * invN - mean.w * mean.w + BN_EPS) * g.w;

    const int quad0  = blockIdx.x * 4 + wave;
    const int qstride = gridDim.x * 4;
    const int nquads = N_NODES / 4;

    for (int quad = quad0; quad < nquads; quad += qstride) {
        const int n = quad * 4 + sub;
        const size_t off = (size_t)n * 64 + 4 * l;
        const float4 h  = *reinterpret_cast<const float4*>(h0 + off);
        const float4 xx = *reinterpret_cast<const float4*>(x + off);
        float4 y;
        y.x = fmaxf((h.x - mean.x) * a.x + bt.x, 0.f) + xx.x;
        y.y = fmaxf((h.y - mean.y) * a.y + bt.y, 0.f) + xx.y;
        y.z = fmaxf((h.z - mean.z) * a.z + bt.z, 0.f) + xx.z;
        y.w = fmaxf((h.w - mean.w) * a.w + bt.w, 0.f) + xx.w;
        *reinterpret_cast<float4*>(h0 + off) = y;
    }
}

// ---------------------------------------------------------------------------
extern "C" void kernel_launch(void* const* d_in, const int* in_sizes, int n_in,
                              void* d_out, int out_size, void* d_ws, size_t ws_size,
                              hipStream_t stream)
{
    const float* x     = (const float*)d_in[0];
    const int*   ei    = (const int*)d_in[1];
    const float* Wk    = (const float*)d_in[2];
    const float* bk    = (const float*)d_in[3];
    const float* Wq    = (const float*)d_in[4];
    const float* bq    = (const float*)d_in[5];
    const float* Wv    = (const float*)d_in[6];
    const float* bv    = (const float*)d_in[7];
    const float* Ws    = (const float*)d_in[8];
    const float* bs    = (const float*)d_in[9];
    const float* gamma = (const float*)d_in[10];
    const float* beta  = (const float*)d_in[11];

    char* w = (char*)d_ws;
    unsigned int*   qv   = (unsigned int*)w;
    unsigned short* kpl  = (unsigned short*)(w + 25600000);
    float* stats      = (float*)(w + 38400000);
    int*   blockhist  = (int*)  (w + 38400512);
    int*   chunk_sums = (int*)  (w + 38601216);
    int*   chunk_off  = (int*)  (w + 38601608);
    int*   row_start  = (int*)  (w + 38602000);
    unsigned int* tmp = (unsigned int*)(w + 39002004);

    float* h0 = (float*)d_out;

    hipMemsetAsync(stats, 0, 128 * sizeof(float), stream);

    // fused: MFMA linears (blocks 0..1562) + bucket histogram (blocks 1563..1758)
    gemm4_count_kernel<<<GEMM_BLOCKS + NBLK_E, 256, 0, stream>>>(
        x, Wk, bk, Wq, bq, Wv, bv, Ws, bs, qv, kpl, h0, ei, blockhist);

    scan1_kernel<<<NCHUNK_H, 256, 0, stream>>>(blockhist, chunk_sums, HIST_TOTAL);
    scan2_kernel<<<1, 256, 0, stream>>>(chunk_sums, chunk_off, NCHUNK_H);
    scan3_kernel<<<NCHUNK_H, 256, 0, stream>>>(blockhist, chunk_off, HIST_TOTAL);
    bucket_scatter_kernel<<<NBLK_E, 256, 0, stream>>>(ei, blockhist, tmp);
    bucket_sort_kernel<<<196, 512, 0, stream>>>(blockhist, tmp, row_start);

    gather_kernel<<<2084, 256, 0, stream>>>(qv, kpl, row_start, (const int*)tmp, h0, stats);

    final_kernel<<<2084, 256, 0, stream>>>(h0, x, stats, gamma, beta);
}

// Round 8
// 186.597 us; speedup vs baseline: 2.7448x; 1.0740x over previous
//
#include <hip/hip_runtime.h>
#include <hip/hip_bf16.h>
#include <math.h>

#define N_NODES 100000
#define N_EDGES 1600000
#define D_FEAT  64
#define BN_EPS  1e-5f

#define NBUCKET_PAD 256      // padded bucket slots (196 used)
#define BUCKET_SHIFT 9       // 512 nodes per bucket
#define NBLK_E  196          // blocks in edge passes
#define EPB     8192         // edges per block (196*8192 >= E)
#define HIST_TOTAL (NBUCKET_PAD * NBLK_E)   // 50176
#define NCHUNK_H 98          // HIST_TOTAL / 512
#define DCAP    14336        // bucket staging cap (mean 8192, sd ~90)
#define GEMM_BLOCKS 1563     // ceil(N_NODES / 64)

typedef __attribute__((ext_vector_type(8))) short bf16x8;
typedef __attribute__((ext_vector_type(4))) float f32x4;

static __device__ __forceinline__ short f2bf(float f) {
    __hip_bfloat16 h = __float2bfloat16(f);
    return __builtin_bit_cast(short, h);
}

// ws layout (byte offsets):
//   0         : mix plane, [N] rows of 192 B: 64 B q-fp8(e4m3) + 128 B v-bf16
//               (19,200,000)
//   19200000  : k plane,  [N][64] bf16                      (12,800,000)
//   32000000  : stats fp32[128]                             (512)
//   32000512  : blockhist int[256*196]                      (200,704)
//   32201216  : chunk_sums int[98]
//   32201608  : chunk_off int[98]
//   32202000  : row_start int[N+1]                          (400,004)
//   32602004  : tmp/sorted_src u32[E] (in-place reuse)      (6,400,000)

// ---------------------------------------------------------------------------
// Kernel 1 (fused): blocks [0,GEMM_BLOCKS) = four bf16 MFMA linears with
// LDS-repacked coalesced epilogue (q converted to fp8 at flush); blocks
// [GEMM_BLOCKS, +NBLK_E) = edge bucket histogram (hidden under the GEMM).
// ---------------------------------------------------------------------------
__global__ __launch_bounds__(256) void gemm4_count_kernel(
    const float* __restrict__ x,
    const float* __restrict__ Wk, const float* __restrict__ bk,
    const float* __restrict__ Wq, const float* __restrict__ bq,
    const float* __restrict__ Wv, const float* __restrict__ bv,
    const float* __restrict__ Ws, const float* __restrict__ bs,
    unsigned char* __restrict__ mix,    // [N] 192-B rows (q fp8 | v bf16)
    unsigned short* __restrict__ kp,    // [N][64] bf16 bits
    float* __restrict__ h0,             // [N][64] fp32 (== d_out)
    const int* __restrict__ ei, int* __restrict__ blockhist)
{
    __shared__ short xs[64 * 64];            // 8 KB staging tile
    __shared__ unsigned short kt[64][68];    // padded repack tiles
    __shared__ unsigned short qt[64][68];
    __shared__ unsigned short vt[64][68];
    __shared__ int hcnt[NBUCKET_PAD];

    // ---------------- bucket-count path ----------------
    if (blockIdx.x >= GEMM_BLOCKS) {
        const int cb = blockIdx.x - GEMM_BLOCKS;
        hcnt[threadIdx.x] = 0;
        __syncthreads();
        const int base = cb * EPB;
        for (int i = threadIdx.x; i < EPB; i += 256) {
            const int e = base + i;
            if (e < N_EDGES) atomicAdd(&hcnt[ei[N_EDGES + e] >> BUCKET_SHIFT], 1);
        }
        __syncthreads();
        blockhist[threadIdx.x * NBLK_E + cb] = hcnt[threadIdx.x];
        return;
    }

    // ---------------- GEMM path ----------------
    const int lane = threadIdx.x & 63;
    const int wave = threadIdx.x >> 6;
    const int r0 = blockIdx.x * 64;

    const float* W; const float* b;
    if      (wave == 0) { W = Wk; b = bk; }
    else if (wave == 1) { W = Wq; b = bq; }
    else if (wave == 2) { W = Wv; b = bv; }
    else                { W = Ws; b = bs; }

    const int bcol = lane & 15;
    const int bk0  = (lane >> 4) * 8;
    bf16x8 bfrag[4][2];
    #pragma unroll
    for (int nt = 0; nt < 4; ++nt) {
        #pragma unroll
        for (int ks = 0; ks < 2; ++ks) {
            const float* wp = W + (nt * 16 + bcol) * 64 + ks * 32 + bk0;
            const float4 w0 = *reinterpret_cast<const float4*>(wp);
            const float4 w1 = *reinterpret_cast<const float4*>(wp + 4);
            bf16x8 f;
            f[0] = f2bf(w0.x); f[1] = f2bf(w0.y); f[2] = f2bf(w0.z); f[3] = f2bf(w0.w);
            f[4] = f2bf(w1.x); f[5] = f2bf(w1.y); f[6] = f2bf(w1.z); f[7] = f2bf(w1.w);
            bfrag[nt][ks] = f;
        }
    }
    float biasv[4];
    #pragma unroll
    for (int nt = 0; nt < 4; ++nt) biasv[nt] = b[nt * 16 + bcol];

    {
        const int row = threadIdx.x >> 2;
        const int qd  = threadIdx.x & 3;
        const int grow = r0 + row;
        float4 t0, t1, t2, t3;
        if (grow < N_NODES) {
            const float* xp = x + (size_t)grow * 64 + qd * 16;
            t0 = reinterpret_cast<const float4*>(xp)[0];
            t1 = reinterpret_cast<const float4*>(xp)[1];
            t2 = reinterpret_cast<const float4*>(xp)[2];
            t3 = reinterpret_cast<const float4*>(xp)[3];
        } else {
            t0 = t1 = t2 = t3 = make_float4(0.f, 0.f, 0.f, 0.f);
        }
        bf16x8 u0, u1;
        u0[0] = f2bf(t0.x); u0[1] = f2bf(t0.y); u0[2] = f2bf(t0.z); u0[3] = f2bf(t0.w);
        u0[4] = f2bf(t1.x); u0[5] = f2bf(t1.y); u0[6] = f2bf(t1.z); u0[7] = f2bf(t1.w);
        u1[0] = f2bf(t2.x); u1[1] = f2bf(t2.y); u1[2] = f2bf(t2.z); u1[3] = f2bf(t2.w);
        u1[4] = f2bf(t3.x); u1[5] = f2bf(t3.y); u1[6] = f2bf(t3.z); u1[7] = f2bf(t3.w);
        const int sw = row & 7;
        *reinterpret_cast<bf16x8*>(xs + row * 64 + (((qd * 2)     ^ sw) * 8)) = u0;
        *reinterpret_cast<bf16x8*>(xs + row * 64 + (((qd * 2 + 1) ^ sw) * 8)) = u1;
    }
    __syncthreads();

    f32x4 acc[4][4];
    #pragma unroll
    for (int mt = 0; mt < 4; ++mt)
        #pragma unroll
        for (int nt = 0; nt < 4; ++nt)
            acc[mt][nt] = (f32x4){biasv[nt], biasv[nt], biasv[nt], biasv[nt]};

    const int arow = lane & 15;
    const int ak   = lane >> 4;
    #pragma unroll
    for (int mt = 0; mt < 4; ++mt) {
        const int row = mt * 16 + arow;
        const int sw = row & 7;
        const bf16x8 a0 = *reinterpret_cast<const bf16x8*>(xs + row * 64 + ((ak       ^ sw) * 8));
        const bf16x8 a1 = *reinterpret_cast<const bf16x8*>(xs + row * 64 + (((4 + ak) ^ sw) * 8));
        #pragma unroll
        for (int nt = 0; nt < 4; ++nt) {
            acc[mt][nt] = __builtin_amdgcn_mfma_f32_16x16x32_bf16(
                a0, bfrag[nt][0], acc[mt][nt], 0, 0, 0);
            acc[mt][nt] = __builtin_amdgcn_mfma_f32_16x16x32_bf16(
                a1, bfrag[nt][1], acc[mt][nt], 0, 0, 0);
        }
    }

    // epilogue: waves 0/1/2 stash bf16 results in LDS; wave 3 stores h0 fp32.
    const int crow0 = (lane >> 4) * 4;
    const int ccol  = lane & 15;
    if (wave < 3) {
        unsigned short (*tile)[68] = (wave == 0) ? kt : (wave == 1) ? qt : vt;
        #pragma unroll
        for (int mt = 0; mt < 4; ++mt)
            #pragma unroll
            for (int nt = 0; nt < 4; ++nt)
                #pragma unroll
                for (int r = 0; r < 4; ++r)
                    tile[mt * 16 + crow0 + r][nt * 16 + ccol] =
                        (unsigned short)f2bf(acc[mt][nt][r]);
    } else {
        #pragma unroll
        for (int mt = 0; mt < 4; ++mt)
            #pragma unroll
            for (int nt = 0; nt < 4; ++nt)
                #pragma unroll
                for (int r = 0; r < 4; ++r) {
                    const int grow = r0 + mt * 16 + crow0 + r;
                    if (grow < N_NODES)
                        h0[(size_t)grow * 64 + nt * 16 + ccol] = acc[mt][nt][r];
                }
    }
    __syncthreads();

    // cooperative coalesced flush: thread -> (row, 16-feature segment)
    {
        const int row = threadIdx.x >> 2;
        const int seg = threadIdx.x & 3;
        const int grow = r0 + row;
        if (grow < N_NODES) {
            const int c0 = seg * 16;
            unsigned char* mrow = mix + (size_t)grow * 192;

            // q -> fp8 e4m3 (16 bytes per seg)
            unsigned int qd[4];
            #pragma unroll
            for (int i = 0; i < 4; ++i) {
                const float f0 = __uint_as_float((unsigned int)qt[row][c0 + 4*i + 0] << 16);
                const float f1 = __uint_as_float((unsigned int)qt[row][c0 + 4*i + 1] << 16);
                const float f2 = __uint_as_float((unsigned int)qt[row][c0 + 4*i + 2] << 16);
                const float f3 = __uint_as_float((unsigned int)qt[row][c0 + 4*i + 3] << 16);
                int p = __builtin_amdgcn_cvt_pk_fp8_f32(f0, f1, 0, false);
                p = __builtin_amdgcn_cvt_pk_fp8_f32(f2, f3, p, true);
                qd[i] = (unsigned int)p;
            }
            *reinterpret_cast<uint4*>(mrow + c0) =
                make_uint4(qd[0], qd[1], qd[2], qd[3]);

            // v -> bf16 (32 bytes per seg)
            unsigned int vd[8];
            #pragma unroll
            for (int i = 0; i < 8; ++i)
                vd[i] = (unsigned int)vt[row][c0 + 2 * i] |
                        ((unsigned int)vt[row][c0 + 2 * i + 1] << 16);
            uint4* vdst = reinterpret_cast<uint4*>(mrow + 64 + seg * 32);
            vdst[0] = make_uint4(vd[0], vd[1], vd[2], vd[3]);
            vdst[1] = make_uint4(vd[4], vd[5], vd[6], vd[7]);

            // k -> bf16 plane (32 bytes per seg)
            unsigned int kd[8];
            #pragma unroll
            for (int i = 0; i < 8; ++i)
                kd[i] = (unsigned int)kt[row][c0 + 2 * i] |
                        ((unsigned int)kt[row][c0 + 2 * i + 1] << 16);
            uint4* kdst = reinterpret_cast<uint4*>(kp + (size_t)grow * 64 + c0);
            kdst[0] = make_uint4(kd[0], kd[1], kd[2], kd[3]);
            kdst[1] = make_uint4(kd[4], kd[5], kd[6], kd[7]);
        }
    }
}

// ---------------------------------------------------------------------------
// CSR build: scans + scatter + per-bucket counting sort (unchanged).
// ---------------------------------------------------------------------------
__global__ __launch_bounds__(256) void scan1_kernel(
    int* __restrict__ buf, int* __restrict__ chunk_sums, int total)
{
    __shared__ int sh[256];
    const int t = threadIdx.x;
    const int base = blockIdx.x * 512;
    const int i0 = base + 2 * t, i1 = base + 2 * t + 1;
    const int a = (i0 < total) ? buf[i0] : 0;
    const int b = (i1 < total) ? buf[i1] : 0;
    const int s = a + b;
    sh[t] = s;
    __syncthreads();
    for (int off = 1; off < 256; off <<= 1) {
        const int val = (t >= off) ? sh[t - off] : 0;
        __syncthreads();
        sh[t] += val;
        __syncthreads();
    }
    const int excl = sh[t] - s;
    if (i0 < total) buf[i0] = excl;
    if (i1 < total) buf[i1] = excl + a;
    if (t == 255) chunk_sums[blockIdx.x] = sh[255];
}

__global__ __launch_bounds__(256) void scan2_kernel(
    const int* __restrict__ chunk_sums, int* __restrict__ chunk_off, int nchunk)
{
    __shared__ int sh[256];
    const int t = threadIdx.x;
    const int v = (t < nchunk) ? chunk_sums[t] : 0;
    sh[t] = v;
    __syncthreads();
    for (int off = 1; off < 256; off <<= 1) {
        const int val = (t >= off) ? sh[t - off] : 0;
        __syncthreads();
        sh[t] += val;
        __syncthreads();
    }
    if (t < nchunk) chunk_off[t] = sh[t] - v;
}

__global__ __launch_bounds__(256) void scan3_kernel(
    int* __restrict__ buf, const int* __restrict__ chunk_off, int total)
{
    const int off = chunk_off[blockIdx.x];
    const int base = blockIdx.x * 512;
    #pragma unroll
    for (int k = 0; k < 2; ++k) {
        const int i = base + k * 256 + threadIdx.x;
        if (i < total) buf[i] += off;
    }
}

__global__ __launch_bounds__(256) void bucket_scatter_kernel(
    const int* __restrict__ ei, const int* __restrict__ blockhist,
    unsigned int* __restrict__ tmp)
{
    __shared__ int cur[NBUCKET_PAD];
    cur[threadIdx.x] = blockhist[threadIdx.x * NBLK_E + blockIdx.x];
    __syncthreads();
    const int base = blockIdx.x * EPB;
    for (int i = threadIdx.x; i < EPB; i += 256) {
        const int e = base + i;
        if (e < N_EDGES) {
            const int s = ei[e];
            const int d = ei[N_EDGES + e];
            const int pos = atomicAdd(&cur[d >> BUCKET_SHIFT], 1);
            tmp[pos] = ((unsigned int)s << BUCKET_SHIFT) | (unsigned int)(d & 511);
        }
    }
}

__global__ __launch_bounds__(512) void bucket_sort_kernel(
    const int* __restrict__ blockhist,
    unsigned int* __restrict__ tmp,
    int* __restrict__ row_start)
{
    __shared__ unsigned int stage[DCAP];
    __shared__ int hist[512];
    __shared__ int cursor[512];
    const int b = blockIdx.x;
    const int t = threadIdx.x;
    const int bstart = blockhist[b * NBLK_E];
    const int bend   = blockhist[(b + 1) * NBLK_E];
    int sz = bend - bstart;
    if (sz > DCAP) sz = DCAP;
    for (int i = t; i < sz; i += 512) stage[i] = tmp[bstart + i];
    hist[t] = 0;
    __syncthreads();
    for (int i = t; i < sz; i += 512) atomicAdd(&hist[stage[i] & 511], 1);
    __syncthreads();
    const int myv = hist[t];
    for (int off = 1; off < 512; off <<= 1) {
        const int u = (t >= off) ? hist[t - off] : 0;
        __syncthreads();
        hist[t] += u;
        __syncthreads();
    }
    const int excl = hist[t] - myv;
    const int node = b * 512 + t;
    if (node <= N_NODES) row_start[node] = bstart + excl;
    cursor[t] = excl;
    __syncthreads();
    for (int i = t; i < sz; i += 512) {
        const unsigned int pk = stage[i];
        const int pos = atomicAdd(&cursor[(int)(pk & 511)], 1);
        tmp[bstart + pos] = pk >> BUCKET_SHIFT;
    }
}

// ---------------------------------------------------------------------------
// Gather: 4 nodes per wave (16 lanes/node, 4 features/lane); mixed-precision
// row gather (q fp8 + v bf16, 192 B = 3 cache lines per row); fused BN stats.
// ---------------------------------------------------------------------------
static __device__ __forceinline__ void edge4(
    float4& acc, const float4& kf, unsigned int qb, uint2 vb)
{
    const float q0 = __builtin_amdgcn_cvt_f32_fp8(qb, 0);
    const float q1 = __builtin_amdgcn_cvt_f32_fp8(qb, 1);
    const float q2 = __builtin_amdgcn_cvt_f32_fp8(qb, 2);
    const float q3 = __builtin_amdgcn_cvt_f32_fp8(qb, 3);
    const float v0 = __uint_as_float(vb.x << 16);
    const float v1 = __uint_as_float(vb.x & 0xffff0000u);
    const float v2 = __uint_as_float(vb.y << 16);
    const float v3 = __uint_as_float(vb.y & 0xffff0000u);
    acc.x = fmaf(__builtin_amdgcn_rcpf(1.0f + __expf(-(kf.x + q0))), v0, acc.x);
    acc.y = fmaf(__builtin_amdgcn_rcpf(1.0f + __expf(-(kf.y + q1))), v1, acc.y);
    acc.z = fmaf(__builtin_amdgcn_rcpf(1.0f + __expf(-(kf.z + q2))), v2, acc.z);
    acc.w = fmaf(__builtin_amdgcn_rcpf(1.0f + __expf(-(kf.w + q3))), v3, acc.w);
}

__global__ __launch_bounds__(256, 4) void gather_kernel(
    const unsigned char* __restrict__ mix,
    const unsigned short* __restrict__ kp,
    const int* __restrict__ row_start,
    const int* __restrict__ sorted_src,
    float* __restrict__ h0, float* __restrict__ stats)
{
    const int lane = threadIdx.x & 63;
    const int sub  = lane >> 4;
    const int l    = lane & 15;
    const int wave = threadIdx.x >> 6;

    float4 lsum = make_float4(0.f, 0.f, 0.f, 0.f);
    float4 lsq  = make_float4(0.f, 0.f, 0.f, 0.f);

    const int quad0  = blockIdx.x * 4 + wave;
    const int qstride = gridDim.x * 4;
    const int nquads = N_NODES / 4;

    for (int quad = quad0; quad < nquads; quad += qstride) {
        const int n = quad * 4 + sub;
        const int base = row_start[n];
        const int end  = row_start[n + 1];
        const int deg  = end - base;

        int m1 = max(deg, __shfl_xor(deg, 16));
        const int maxdeg = max(m1, __shfl_xor(m1, 32));

        const ushort4 kr = *reinterpret_cast<const ushort4*>(kp + (size_t)n * 64 + 4 * l);
        float4 kf;
        kf.x = __uint_as_float((unsigned int)kr.x << 16);
        kf.y = __uint_as_float((unsigned int)kr.y << 16);
        kf.z = __uint_as_float((unsigned int)kr.z << 16);
        kf.w = __uint_as_float((unsigned int)kr.w << 16);
        float4 acc = *reinterpret_cast<const float4*>(h0 + (size_t)n * 64 + 4 * l);

        const int safe_last = max(min(end - 1, N_EDGES - 1), 0);

        for (int t = 0; t < maxdeg; t += 4) {
            const int i0 = min(base + t + 0, safe_last);
            const int i1 = min(base + t + 1, safe_last);
            const int i2 = min(base + t + 2, safe_last);
            const int i3 = min(base + t + 3, safe_last);
            const size_t r0 = (size_t)sorted_src[i0] * 192;
            const size_t r1 = (size_t)sorted_src[i1] * 192;
            const size_t r2 = (size_t)sorted_src[i2] * 192;
            const size_t r3 = (size_t)sorted_src[i3] * 192;
            const unsigned int qb0 = *reinterpret_cast<const unsigned int*>(mix + r0 + 4 * l);
            const unsigned int qb1 = *reinterpret_cast<const unsigned int*>(mix + r1 + 4 * l);
            const unsigned int qb2 = *reinterpret_cast<const unsigned int*>(mix + r2 + 4 * l);
            const unsigned int qb3 = *reinterpret_cast<const unsigned int*>(mix + r3 + 4 * l);
            uint2 vb0 = *reinterpret_cast<const uint2*>(mix + r0 + 64 + 8 * l);
            uint2 vb1 = *reinterpret_cast<const uint2*>(mix + r1 + 64 + 8 * l);
            uint2 vb2 = *reinterpret_cast<const uint2*>(mix + r2 + 64 + 8 * l);
            uint2 vb3 = *reinterpret_cast<const uint2*>(mix + r3 + 64 + 8 * l);
            // mask invalid edge slots: v=0 -> zero contribution (q need not be
            // masked: clamped index points at a real, finite q row)
            const bool m0 = (t + 0) < deg, m1b = (t + 1) < deg,
                       m2 = (t + 2) < deg, m3 = (t + 3) < deg;
            vb0.x = m0 ? vb0.x : 0u;  vb0.y = m0 ? vb0.y : 0u;
            vb1.x = m1b ? vb1.x : 0u; vb1.y = m1b ? vb1.y : 0u;
            vb2.x = m2 ? vb2.x : 0u;  vb2.y = m2 ? vb2.y : 0u;
            vb3.x = m3 ? vb3.x : 0u;  vb3.y = m3 ? vb3.y : 0u;

            edge4(acc, kf, qb0, vb0);
            edge4(acc, kf, qb1, vb1);
            edge4(acc, kf, qb2, vb2);
            edge4(acc, kf, qb3, vb3);
        }

        *reinterpret_cast<float4*>(h0 + (size_t)n * 64 + 4 * l) = acc;
        lsum.x += acc.x; lsum.y += acc.y; lsum.z += acc.z; lsum.w += acc.w;
        lsq.x += acc.x * acc.x; lsq.y += acc.y * acc.y;
        lsq.z += acc.z * acc.z; lsq.w += acc.w * acc.w;
    }

    __shared__ float bsum[64];
    __shared__ float bsq[64];
    if (threadIdx.x < 64) { bsum[threadIdx.x] = 0.f; bsq[threadIdx.x] = 0.f; }
    __syncthreads();
    atomicAdd(&bsum[4 * l + 0], lsum.x); atomicAdd(&bsq[4 * l + 0], lsq.x);
    atomicAdd(&bsum[4 * l + 1], lsum.y); atomicAdd(&bsq[4 * l + 1], lsq.y);
    atomicAdd(&bsum[4 * l + 2], lsum.z); atomicAdd(&bsq[4 * l + 2], lsq.z);
    atomicAdd(&bsum[4 * l + 3], lsum.w); atomicAdd(&bsq[4 * l + 3], lsq.w);
    __syncthreads();
    if (threadIdx.x < 64) {
        atomicAdd(&stats[threadIdx.x], bsum[threadIdx.x]);
        atomicAdd(&stats[64 + threadIdx.x], bsq[threadIdx.x]);
    }
}

// ---------------------------------------------------------------------------
// Final: BN + ReLU + residual; quad mapping mirrors gather; float4 everywhere.
// ---------------------------------------------------------------------------
__global__ __launch_bounds__(256) void final_kernel(
    float* __restrict__ h0, const float* __restrict__ x,
    const float* __restrict__ stats,
    const float* __restrict__ gamma, const float* __restrict__ beta)
{
    const int lane = threadIdx.x & 63;
    const int sub  = lane >> 4;
    const int l    = lane & 15;
    const int wave = threadIdx.x >> 6;

    const float invN = 1.0f / (float)N_NODES;
    const float4 s1 = *reinterpret_cast<const float4*>(stats + 4 * l);
    const float4 s2 = *reinterpret_cast<const float4*>(stats + 64 + 4 * l);
    const float4 g  = *reinterpret_cast<const float4*>(gamma + 4 * l);
    const float4 bt = *reinterpret_cast<const float4*>(beta + 4 * l);
    float4 mean, a;
    mean.x = s1.x * invN; mean.y = s1.y * invN;
    mean.z = s1.z * invN; mean.w = s1.w * invN;
    a.x = rsqrtf(s2.x * invN - mean.x * mean.x + BN_EPS) * g.x;
    a.y = rsqrtf(s2.y * invN - mean.y * mean.y + BN_EPS) * g.y;
    a.z = rsqrtf(s2.z * invN - mean.z * mean.z + BN_EPS) * g.z;
    a.w = rsqrtf(s2.w * invN - mean.w * mean.w + BN_EPS) * g.w;

    const int quad0  = blockIdx.x * 4 + wave;
    const int qstride = gridDim.x * 4;
    const int nquads = N_NODES / 4;

    for (int quad = quad0; quad < nquads; quad += qstride) {
        const int n = quad * 4 + sub;
        const size_t off = (size_t)n * 64 + 4 * l;
        const float4 h  = *reinterpret_cast<const float4*>(h0 + off);
        const float4 xx = *reinterpret_cast<const float4*>(x + off);
        float4 y;
        y.x = fmaxf((h.x - mean.x) * a.x + bt.x, 0.f) + xx.x;
        y.y = fmaxf((h.y - mean.y) * a.y + bt.y, 0.f) + xx.y;
        y.z = fmaxf((h.z - mean.z) * a.z + bt.z, 0.f) + xx.z;
        y.w = fmaxf((h.w - mean.w) * a.w + bt.w, 0.f) + xx.w;
        *reinterpret_cast<float4*>(h0 + off) = y;
    }
}

// ---------------------------------------------------------------------------
extern "C" void kernel_launch(void* const* d_in, const int* in_sizes, int n_in,
                              void* d_out, int out_size, void* d_ws, size_t ws_size,
                              hipStream_t stream)
{
    const float* x     = (const float*)d_in[0];
    const int*   ei    = (const int*)d_in[1];
    const float* Wk    = (const float*)d_in[2];
    const float* bk    = (const float*)d_in[3];
    const float* Wq    = (const float*)d_in[4];
    const float* bq    = (const float*)d_in[5];
    const float* Wv    = (const float*)d_in[6];
    const float* bv    = (const float*)d_in[7];
    const float* Ws    = (const float*)d_in[8];
    const float* bs    = (const float*)d_in[9];
    const float* gamma = (const float*)d_in[10];
    const float* beta  = (const float*)d_in[11];

    char* w = (char*)d_ws;
    unsigned char*  mix  = (unsigned char*)w;               // 19.2 MB
    unsigned short* kpl  = (unsigned short*)(w + 19200000); // 12.8 MB
    float* stats      = (float*)(w + 32000000);
    int*   blockhist  = (int*)  (w + 32000512);
    int*   chunk_sums = (int*)  (w + 32201216);
    int*   chunk_off  = (int*)  (w + 32201608);
    int*   row_start  = (int*)  (w + 32202000);
    unsigned int* tmp = (unsigned int*)(w + 32602004);

    float* h0 = (float*)d_out;

    hipMemsetAsync(stats, 0, 128 * sizeof(float), stream);

    // fused: MFMA linears (blocks 0..1562) + bucket histogram (blocks 1563..1758)
    gemm4_count_kernel<<<GEMM_BLOCKS + NBLK_E, 256, 0, stream>>>(
        x, Wk, bk, Wq, bq, Wv, bv, Ws, bs, mix, kpl, h0, ei, blockhist);

    scan1_kernel<<<NCHUNK_H, 256, 0, stream>>>(blockhist, chunk_sums, HIST_TOTAL);
    scan2_kernel<<<1, 256, 0, stream>>>(chunk_sums, chunk_off, NCHUNK_H);
    scan3_kernel<<<NCHUNK_H, 256, 0, stream>>>(blockhist, chunk_off, HIST_TOTAL);
    bucket_scatter_kernel<<<NBLK_E, 256, 0, stream>>>(ei, blockhist, tmp);
    bucket_sort_kernel<<<196, 512, 0, stream>>>(blockhist, tmp, row_start);

    gather_kernel<<<2084, 256, 0, stream>>>(mix, kpl, row_start, (const int*)tmp, h0, stats);

    final_kernel<<<2084, 256, 0, stream>>>(h0, x, stats, gamma, beta);
}